// Round 12
// baseline (411.713 us; speedup 1.0000x reference)
//
#include <hip/hip_runtime.h>
#include <hip/hip_fp16.h>

// AttentionBlock3D: channel attention. B=4, C=512, N=T*H*W=16384, 8 heads, d=64.
// Algebraic reduction: result = x + M*H + c, with
//   G = H H^T (per batch, SYMMETRIC -> upper tiles only + k_symm mirror),
//   logits = scale*(Wq G Wk^T + rank-1), P = softmax per head,
//   M = out_w * blockdiag(P) * Wv, c = out_w * blockdiag(P) * bv + out_b.
//
// MFMA kernel geometry: LOCKED at measured-best (R9):
//   BK=64 (128B rows, 8x16B slots, XOR-swizzle slot^(row&7) => 0 bank conflicts),
//   single LDS buffer (32 KiB), 2 barriers per K-step, __launch_bounds__(256,2).
//   Measured dead ends: lb(256,4) -39% (R8); BK=32 4-way conflicts (R7);
//   64KB dbuf (R6, R11) and counted-vmcnt (R11) neutral-to-worse; x-prefetch
//   (R10) neutral. This structure runs at its achieved-BW pace (~84us, 240MB).
// R12: non-temporal epilogue in k_out (x load / out store bypass L2 pollution).

#define CCH 512
#define NTOK 16384
#define NHEAD 8

typedef _Float16 f16;
typedef _Float16 f16x8 __attribute__((ext_vector_type(8)));
typedef float f32x4 __attribute__((ext_vector_type(4)));

__device__ __forceinline__ void g2l16(const void* g, void* l) {
  __builtin_amdgcn_global_load_lds((const __attribute__((address_space(1))) void*)g,
                                   (__attribute__((address_space(3))) void*)l,
                                   16, 0, 0);
}

// ---------------- K1: GroupNorm stats (sum, sumsq) per (b, group) ----------------
__global__ __launch_bounds__(256) void k_stats(const float* __restrict__ x,
                                               float* __restrict__ stats) {
  int bg = blockIdx.y;          // b*8 + g  (group region is contiguous: 64 rows * NTOK)
  int chunk = blockIdx.x;       // 0..31
  const float4* p = (const float4*)(x + (size_t)bg * (64ull * NTOK)) + (size_t)chunk * 8192;
  float s = 0.f, q = 0.f;
  for (int i = threadIdx.x; i < 8192; i += 256) {
    float4 v = p[i];
    s += v.x + v.y + v.z + v.w;
    q += v.x * v.x + v.y * v.y + v.z * v.z + v.w * v.w;
  }
  for (int off = 32; off; off >>= 1) { s += __shfl_down(s, off); q += __shfl_down(q, off); }
  __shared__ float ls[4], lq[4];
  int wid = threadIdx.x >> 6, lane = threadIdx.x & 63;
  if (lane == 0) { ls[wid] = s; lq[wid] = q; }
  __syncthreads();
  if (threadIdx.x == 0) {
    atomicAdd(&stats[bg * 2 + 0], ls[0] + ls[1] + ls[2] + ls[3]);
    atomicAdd(&stats[bg * 2 + 1], lq[0] + lq[1] + lq[2] + lq[3]);
  }
}

// ---------------- K2: normalize -> H (fp16, [b][c][n]) and Ht (fp16, [b][n][c]), s = H*1 ----
__global__ __launch_bounds__(256) void k_gnorm(const float* __restrict__ x,
                                               const float* __restrict__ gw,
                                               const float* __restrict__ gb,
                                               const float* __restrict__ stats,
                                               f16* __restrict__ H, f16* __restrict__ Ht,
                                               float* __restrict__ svec) {
  int nc = blockIdx.x;   // n chunk (256 tokens)
  int cg = blockIdx.y;   // channel group (64 ch) == GN group
  int b = blockIdx.z;
  int t = threadIdx.x;
  __shared__ f16 T2[64][260];     // [c_local][n_local], 260-half rows (520B: bank stride 2)
  __shared__ float svp[4][64];
  float sum = stats[(b * 8 + cg) * 2], sq = stats[(b * 8 + cg) * 2 + 1];
  const float inv = 1.f / (64.f * (float)NTOK);
  float mean = sum * inv;
  float var = fmaxf(sq * inv - mean * mean, 0.f);
  float rsig = rsqrtf(var + 1e-5f);
  int c0 = cg * 64, n0 = nc * 256;
  int tq = t & 63, rr0 = t >> 6;       // lane owns 4 consecutive tokens; wave owns row set
#pragma unroll
  for (int it = 0; it < 16; ++it) {
    int r = it * 4 + rr0;
    int c = c0 + r;
    float a = gw[c] * rsig;
    float bb = gb[c] - mean * a;
    size_t idx = ((size_t)(b * CCH + c)) * NTOK + n0 + tq * 4;
    float4 xv = *(const float4*)&x[idx];
    f16 hh[4] __attribute__((aligned(8)));
    hh[0] = (f16)(xv.x * a + bb);
    hh[1] = (f16)(xv.y * a + bb);
    hh[2] = (f16)(xv.z * a + bb);
    hh[3] = (f16)(xv.w * a + bb);
    *(uint2*)&H[idx] = *(const uint2*)hh;          // 8B store
    *(uint2*)&T2[r][tq * 4] = *(const uint2*)hh;   // 8B LDS write, 2-bank lane stride
  }
  __syncthreads();
  {  // svec partials: 4 quarter-sums per channel, then combine
    int c = t & 63, q = t >> 6;
    float acc = 0.f;
#pragma unroll
    for (int j = 0; j < 64; ++j) acc += (float)T2[c][q * 64 + j];
    svp[q][c] = acc;
  }
  __syncthreads();
  if (t < 64) {
    atomicAdd(&svec[b * CCH + c0 + t],
              svp[0][t] + svp[1][t] + svp[2][t] + svp[3][t]);
  }
  int s8 = t & 7, nl = t >> 3;        // transpose write-out: 8 threads per Ht row
#pragma unroll
  for (int it = 0; it < 8; ++it) {
    int n = it * 32 + nl;
    f16 g[8] __attribute__((aligned(16)));
#pragma unroll
    for (int j = 0; j < 8; ++j) g[j] = T2[s8 * 8 + j][n];
    *(uint4*)&Ht[((size_t)b * NTOK + n0 + n) * CCH + c0 + s8 * 8] = *(const uint4*)g;
  }
}

// ---------------- K3: G = H H^T, upper tiles, split-K=16, BK=64 single-buf (32KB) ----
#define SPLITS 16
__global__ __launch_bounds__(256, 2) void k_syrk(const f16* __restrict__ H,
                                                 float* __restrict__ G) {
  // 10 upper-triangle tiles of 128x128 over the 512x512 output
  const int TI[10] = {0, 0, 0, 0, 1, 1, 1, 2, 2, 3};
  const int TJ[10] = {0, 1, 2, 3, 1, 2, 3, 2, 3, 3};
  int tile = blockIdx.x;
  int split = blockIdx.y;
  int b = blockIdx.z;
  int ii = TI[tile], jj = TJ[tile];
  int m0 = ii * 128, n0 = jj * 128;
  int t = threadIdx.x, lane = t & 63, wid = t >> 6;
  int wr = wid >> 1, wc = wid & 1;
  __shared__ __align__(16) f16 sA[128 * 64];
  __shared__ __align__(16) f16 sB[128 * 64];
  const f16* Hb = H + (size_t)b * CCH * NTOK;
  int k0 = split * (NTOK / SPLITS);     // 1024 per split
  f32x4 acc[4][4] = {};
  int ldsrow = wid * 8 + (lane >> 3);   // 128B rows: 8 lanes/row
  int slot = lane & 7;                  // 16B slot within row
  int lr = lane & 15, lk = lane >> 4;

  const int NS = (NTOK / SPLITS) / 64;  // 16 K-steps of BK=64
  for (int ks = 0; ks < NS; ++ks) {
    int kk0 = k0 + ks * 64;
    __syncthreads();
#pragma unroll
    for (int i = 0; i < 4; ++i) {
      int row = ldsrow + i * 32;
      int cA = ((slot ^ (row & 7)) * 8);  // pre-swizzled global source column
      g2l16(Hb + (size_t)(m0 + row) * NTOK + kk0 + cA, &sA[i * 2048 + wid * 512]);
      g2l16(Hb + (size_t)(n0 + row) * NTOK + kk0 + cA, &sB[i * 2048 + wid * 512]);
    }
    asm volatile("s_waitcnt vmcnt(0)" ::: "memory");
    __syncthreads();
#pragma unroll
    for (int kk = 0; kk < 2; ++kk) {
      f16x8 af[4], bf[4];
#pragma unroll
      for (int mi = 0; mi < 4; ++mi) {
        int row = wr * 64 + mi * 16 + lr;
        int ks8 = (kk * 4 + lk) ^ (row & 7);
        af[mi] = *(const f16x8*)&sA[row * 64 + ks8 * 8];
      }
#pragma unroll
      for (int ni = 0; ni < 4; ++ni) {
        int row = wc * 64 + ni * 16 + lr;
        int ks8 = (kk * 4 + lk) ^ (row & 7);
        bf[ni] = *(const f16x8*)&sB[row * 64 + ks8 * 8];
      }
#pragma unroll
      for (int mi = 0; mi < 4; ++mi)
#pragma unroll
        for (int ni = 0; ni < 4; ++ni)
          acc[mi][ni] = __builtin_amdgcn_mfma_f32_16x16x32_f16(af[mi], bf[ni], acc[mi][ni], 0, 0, 0);
    }
  }

  float* Gb = G + (size_t)b * CCH * CCH;
#pragma unroll
  for (int mi = 0; mi < 4; ++mi)
#pragma unroll
    for (int j = 0; j < 4; ++j) {
      int rr2 = m0 + wr * 64 + mi * 16 + lk * 4 + j;
#pragma unroll
      for (int ni = 0; ni < 4; ++ni) {
        int cc = n0 + wc * 64 + ni * 16 + lr;
        atomicAdd(&Gb[(size_t)rr2 * CCH + cc], acc[mi][ni][j]);   // coalesced rows only
      }
    }
}

// ---------------- K3b: mirror upper off-diag tiles to lower triangle ----------------
__global__ __launch_bounds__(256) void k_symm(float* __restrict__ G) {
  // 6 off-diag 128-tiles x 4 subtiles of 64x64 = 24 subtiles per batch
  const int TI6[6] = {0, 0, 0, 1, 1, 2};
  const int TJ6[6] = {1, 2, 3, 2, 3, 3};
  int bx = blockIdx.x;               // 0..23
  int b = blockIdx.y;
  int t6 = bx >> 2, sub = bx & 3;
  int ib = TI6[t6] * 2 + (sub >> 1); // source 64-row block
  int jb = TJ6[t6] * 2 + (sub & 1);  // source 64-col block
  float* Gb = G + (size_t)b * CCH * CCH;
  __shared__ float s[64][65];
  int t = threadIdx.x;
  int r = t >> 2, cg = (t & 3) * 16;
  const float* src = &Gb[(size_t)(ib * 64 + r) * CCH + jb * 64 + cg];
#pragma unroll
  for (int k = 0; k < 4; ++k) {
    float4 v = *(const float4*)(src + k * 4);
    s[r][cg + k * 4 + 0] = v.x; s[r][cg + k * 4 + 1] = v.y;
    s[r][cg + k * 4 + 2] = v.z; s[r][cg + k * 4 + 3] = v.w;
  }
  __syncthreads();
  float* dst = &Gb[(size_t)(jb * 64 + r) * CCH + ib * 64 + cg];
#pragma unroll
  for (int k = 0; k < 4; ++k) {
    float4 v;
    v.x = s[cg + k * 4 + 0][r]; v.y = s[cg + k * 4 + 1][r];
    v.z = s[cg + k * 4 + 2][r]; v.w = s[cg + k * 4 + 3][r];
    *(float4*)(dst + k * 4) = v;
  }
}

// ---------------- K4a/K4c: fp32 512x512x512 GEMM, C[b] = A @ B[b] ----------------
template <bool HALF_OUT>
__global__ __launch_bounds__(256) void k_sgemm512(const float* __restrict__ A,
                                                  const float* __restrict__ Bm,
                                                  void* __restrict__ Cv,
                                                  size_t strideB, size_t strideC) {
  int n0 = blockIdx.x * 64, m0 = blockIdx.y * 64, b = blockIdx.z;
  const float* Bb = Bm + (size_t)b * strideB;
  int t = threadIdx.x;
  int rm = t >> 4, rn = t & 15;
  __shared__ float sA[16][68];  // [k][m] transposed
  __shared__ float sB[16][68];  // [k][n]
  float acc[4][4] = {};
  for (int k0 = 0; k0 < 512; k0 += 16) {
#pragma unroll
    for (int i = 0; i < 4; ++i) {
      int idx = i * 256 + t;
      int mrow = idx >> 4, kc = idx & 15;
      sA[kc][mrow] = A[(size_t)(m0 + mrow) * CCH + k0 + kc];
      int krow = idx >> 6, ncc = idx & 63;
      sB[krow][ncc] = Bb[(size_t)(k0 + krow) * CCH + n0 + ncc];
    }
    __syncthreads();
#pragma unroll
    for (int k = 0; k < 16; ++k) {
      float4 a4 = *(const float4*)&sA[k][rm * 4];
      float4 b4 = *(const float4*)&sB[k][rn * 4];
      acc[0][0] += a4.x * b4.x; acc[0][1] += a4.x * b4.y; acc[0][2] += a4.x * b4.z; acc[0][3] += a4.x * b4.w;
      acc[1][0] += a4.y * b4.x; acc[1][1] += a4.y * b4.y; acc[1][2] += a4.y * b4.z; acc[1][3] += a4.y * b4.w;
      acc[2][0] += a4.z * b4.x; acc[2][1] += a4.z * b4.y; acc[2][2] += a4.z * b4.z; acc[2][3] += a4.z * b4.w;
      acc[3][0] += a4.w * b4.x; acc[3][1] += a4.w * b4.y; acc[3][2] += a4.w * b4.z; acc[3][3] += a4.w * b4.w;
    }
    __syncthreads();
  }
  if constexpr (HALF_OUT) {
    f16* Cc = ((f16*)Cv) + (size_t)b * strideC;
#pragma unroll
    for (int i = 0; i < 4; ++i)
#pragma unroll
      for (int j = 0; j < 4; ++j)
        Cc[(size_t)(m0 + rm * 4 + i) * CCH + n0 + rn * 4 + j] = (f16)acc[i][j];
  } else {
    float* Cc = ((float*)Cv) + (size_t)b * strideC;
#pragma unroll
    for (int i = 0; i < 4; ++i)
#pragma unroll
      for (int j = 0; j < 4; ++j)
        Cc[(size_t)(m0 + rm * 4 + i) * CCH + n0 + rn * 4 + j] = acc[i][j];
  }
}

// ---------------- K4b-1: uvec[b][0:512]=Wq@s, [512:1024]=Wk@s (4 lanes/output) ----
__global__ __launch_bounds__(256) void k_uvec(const float* __restrict__ qkvw,
                                              const float* __restrict__ svec,
                                              float* __restrict__ uvec) {
  int o = blockIdx.x * 64 + (threadIdx.x >> 2);   // grid.x = 16
  int l = threadIdx.x & 3;
  int b = blockIdx.y;
  __shared__ float ss[512];
  for (int i = threadIdx.x; i < 512; i += 256) ss[i] = svec[b * CCH + i];
  __syncthreads();
  const float* wr_ = qkvw + (size_t)o * CCH + l * 128;
  const float* sp = ss + l * 128;
  float a = 0.f;
#pragma unroll
  for (int i = 0; i < 32; ++i) {
    float4 w = *(const float4*)&wr_[i * 4];
    a += w.x * sp[i * 4] + w.y * sp[i * 4 + 1] + w.z * sp[i * 4 + 2] + w.w * sp[i * 4 + 3];
  }
  a += __shfl_down(a, 2);
  a += __shfl_down(a, 1);
  if (l == 0) uvec[b * 1024 + o] = a;
}

// ---------------- K4b-2: L[b,h] += T1_h[64xK-chunk] @ Wk_h^T (split-K, atomics) ----
__global__ __launch_bounds__(256) void k_logits(const float* __restrict__ T1,
                                                const float* __restrict__ qkvw,
                                                float* __restrict__ L) {
  int kc = blockIdx.x;     // 8 chunks of 64 k
  int h = blockIdx.y, b = blockIdx.z;
  int t = threadIdx.x;
  int h64 = h * 64, k0 = kc * 64;
  __shared__ float sT[64][68];   // [d][k]
  __shared__ float sW[64][68];   // [k][e]
#pragma unroll
  for (int i = 0; i < 16; ++i) {
    int idx = i * 256 + t;
    int r = idx >> 6, c = idx & 63;
    sT[r][c] = T1[((size_t)b * CCH + h64 + r) * CCH + k0 + c];
    sW[c][r] = qkvw[(size_t)(512 + h64 + r) * CCH + k0 + c];
  }
  __syncthreads();
  int d = t >> 2, eg = (t & 3) * 16;
  float acc[16] = {};
  for (int k = 0; k < 64; ++k) {
    float a = sT[d][k];
    float4 w0 = *(const float4*)&sW[k][eg];
    float4 w1 = *(const float4*)&sW[k][eg + 4];
    float4 w2 = *(const float4*)&sW[k][eg + 8];
    float4 w3 = *(const float4*)&sW[k][eg + 12];
    acc[0] += a * w0.x;  acc[1] += a * w0.y;  acc[2] += a * w0.z;  acc[3] += a * w0.w;
    acc[4] += a * w1.x;  acc[5] += a * w1.y;  acc[6] += a * w1.z;  acc[7] += a * w1.w;
    acc[8] += a * w2.x;  acc[9] += a * w2.y;  acc[10] += a * w2.z; acc[11] += a * w2.w;
    acc[12] += a * w3.x; acc[13] += a * w3.y; acc[14] += a * w3.z; acc[15] += a * w3.w;
  }
  float* Lrow = &L[(((size_t)b * NHEAD + h) * 64 + d) * 64 + eg];
#pragma unroll
  for (int i = 0; i < 16; ++i) atomicAdd(&Lrow[i], acc[i]);
}

// ---------------- K4b-3: softmax rows + rank-1 bias terms -> P, pbv ----------------
__global__ __launch_bounds__(64) void k_softmax(const float* __restrict__ L,
                                                const float* __restrict__ uvec,
                                                const float* __restrict__ qkvb,
                                                float* __restrict__ P,
                                                float* __restrict__ pbv) {
  int bh = blockIdx.x;           // b*8 + h
  int b = bh >> 3, h = bh & 7;
  int d = threadIdx.x;           // 0..63
  int h64 = h * 64;
  __shared__ float sbk[64], sbv[64], suk[64];
  sbk[d] = qkvb[512 + h64 + d];
  sbv[d] = qkvb[1024 + h64 + d];
  suk[d] = uvec[b * 1024 + 512 + h64 + d];
  __syncthreads();
  float uq = uvec[b * 1024 + h64 + d];
  float bq = qkvb[h64 + d];
  float l[64];
  const float* Lr = &L[((size_t)bh * 64 + d) * 64];
  float m = -1e30f;
#pragma unroll
  for (int e = 0; e < 64; ++e) {
    float v = (Lr[e] + uq * sbk[e] + bq * suk[e] + 16384.f * bq * sbk[e]) * 0.125f;
    l[e] = v;
    m = fmaxf(m, v);
  }
  float sum = 0.f;
#pragma unroll
  for (int e = 0; e < 64; ++e) { float p = expf(l[e] - m); l[e] = p; sum += p; }
  float r = 1.f / sum, pb = 0.f;
  float* Pr = &P[((size_t)bh * 64 + d) * 64];
#pragma unroll
  for (int e = 0; e < 64; ++e) { float p = l[e] * r; Pr[e] = p; pb += p * sbv[e]; }
  pbv[b * CCH + h64 + d] = pb;
}

// ---------------- K4b-4: R[b, h64+d, c] = sum_e P[b,h,d,e] Wv[h64+e][c] ----------
__global__ __launch_bounds__(256) void k_pv(const float* __restrict__ P,
                                            const float* __restrict__ qkvw,
                                            float* __restrict__ R) {
  int ct = blockIdx.x;     // 8 c-tiles of 64
  int h = blockIdx.y, b = blockIdx.z;
  int t = threadIdx.x;
  int h64 = h * 64, c0 = ct * 64;
  __shared__ float sP[64][68];   // [d][e]
  __shared__ float sW[64][68];   // [e][c]
#pragma unroll
  for (int i = 0; i < 16; ++i) {
    int idx = i * 256 + t;
    int r = idx >> 6, c = idx & 63;
    sP[r][c] = P[(((size_t)b * NHEAD + h) * 64 + r) * 64 + c];
    sW[r][c] = qkvw[(size_t)(1024 + h64 + r) * CCH + c0 + c];
  }
  __syncthreads();
  int d = t >> 2, cg = (t & 3) * 16;
  float r0 = 0, r1 = 0, r2 = 0, r3 = 0, r4 = 0, r5 = 0, r6 = 0, r7 = 0;
  float r8 = 0, r9 = 0, r10 = 0, r11 = 0, r12 = 0, r13 = 0, r14 = 0, r15 = 0;
  for (int e = 0; e < 64; ++e) {
    float p = sP[d][e];
    float4 w0 = *(const float4*)&sW[e][cg];
    float4 w1 = *(const float4*)&sW[e][cg + 4];
    float4 w2 = *(const float4*)&sW[e][cg + 8];
    float4 w3 = *(const float4*)&sW[e][cg + 12];
    r0 += p * w0.x;  r1 += p * w0.y;  r2 += p * w0.z;  r3 += p * w0.w;
    r4 += p * w1.x;  r5 += p * w1.y;  r6 += p * w1.z;  r7 += p * w1.w;
    r8 += p * w2.x;  r9 += p * w2.y;  r10 += p * w2.z; r11 += p * w2.w;
    r12 += p * w3.x; r13 += p * w3.y; r14 += p * w3.z; r15 += p * w3.w;
  }
  float* Rrow = &R[((size_t)b * CCH + h64 + d) * CCH + c0];
  *(float4*)&Rrow[cg + 0]  = make_float4(r0, r1, r2, r3);
  *(float4*)&Rrow[cg + 4]  = make_float4(r4, r5, r6, r7);
  *(float4*)&Rrow[cg + 8]  = make_float4(r8, r9, r10, r11);
  *(float4*)&Rrow[cg + 12] = make_float4(r12, r13, r14, r15);
}

// ---------------- K4d: cvec = out_w @ pbv + out_b (4 lanes/output) ----------------
__global__ __launch_bounds__(256) void k_cvec(const float* __restrict__ outw,
                                              const float* __restrict__ outb,
                                              const float* __restrict__ pbv,
                                              float* __restrict__ cvec) {
  int o = blockIdx.x * 64 + (threadIdx.x >> 2);   // grid.x = 8
  int l = threadIdx.x & 3;
  int b = blockIdx.y;
  __shared__ float sp[512];
  for (int i = threadIdx.x; i < 512; i += 256) sp[i] = pbv[b * CCH + i];
  __syncthreads();
  const float* wr_ = outw + (size_t)o * CCH + l * 128;
  const float* spp = sp + l * 128;
  float a = 0.f;
#pragma unroll
  for (int i = 0; i < 32; ++i) {
    float4 w = *(const float4*)&wr_[i * 4];
    a += w.x * spp[i * 4] + w.y * spp[i * 4 + 1] + w.z * spp[i * 4 + 2] + w.w * spp[i * 4 + 3];
  }
  a += __shfl_down(a, 2);
  a += __shfl_down(a, 1);
  if (l == 0) cvec[b * CCH + o] = a + outb[o];
}

// ---------------- K5: out = x + M16 @ H + cvec (fp16 MFMA, BK=64 single-buf, nt epilogue) ----
__global__ __launch_bounds__(256, 2) void k_out(const f16* __restrict__ M16,
                                                const f16* __restrict__ Ht,
                                                const float* __restrict__ x,
                                                const float* __restrict__ cvec,
                                                float* __restrict__ out) {
  int nt = blockIdx.x;   // 128 n-tiles
  int mt = blockIdx.y;   // 4 o-tiles
  int b = blockIdx.z;
  int m0 = mt * 128, n0 = nt * 128;
  int t = threadIdx.x, lane = t & 63, wid = t >> 6;
  int wr = wid >> 1, wc = wid & 1;
  __shared__ __align__(16) f16 sA[128 * 64];
  __shared__ __align__(16) f16 sB[128 * 64];
  const f16* A = M16 + (size_t)b * CCH * CCH;
  const f16* Bp = Ht + (size_t)b * NTOK * CCH;
  f32x4 acc[4][4] = {};
  int ldsrow = wid * 8 + (lane >> 3);
  int slot = lane & 7;
  int lr = lane & 15, lk = lane >> 4;
  for (int ks = 0; ks < 8; ++ks) {
    int kk0 = ks * 64;
    __syncthreads();
#pragma unroll
    for (int i = 0; i < 4; ++i) {
      int row = ldsrow + i * 32;
      int cA = ((slot ^ (row & 7)) * 8);
      g2l16(A + (size_t)(m0 + row) * CCH + kk0 + cA, &sA[i * 2048 + wid * 512]);
      g2l16(Bp + (size_t)(n0 + row) * CCH + kk0 + cA, &sB[i * 2048 + wid * 512]);
    }
    asm volatile("s_waitcnt vmcnt(0)" ::: "memory");
    __syncthreads();
#pragma unroll
    for (int kk = 0; kk < 2; ++kk) {
      f16x8 af[4], bf[4];
#pragma unroll
      for (int mi = 0; mi < 4; ++mi) {
        int row = wr * 64 + mi * 16 + lr;
        int ks8 = (kk * 4 + lk) ^ (row & 7);
        af[mi] = *(const f16x8*)&sA[row * 64 + ks8 * 8];
      }
#pragma unroll
      for (int ni = 0; ni < 4; ++ni) {
        int row = wc * 64 + ni * 16 + lr;
        int ks8 = (kk * 4 + lk) ^ (row & 7);
        bf[ni] = *(const f16x8*)&sB[row * 64 + ks8 * 8];
      }
#pragma unroll
      for (int mi = 0; mi < 4; ++mi)
#pragma unroll
        for (int ni = 0; ni < 4; ++ni)
          acc[mi][ni] = __builtin_amdgcn_mfma_f32_16x16x32_f16(af[mi], bf[ni], acc[mi][ni], 0, 0, 0);
    }
  }

  const float* xb = x + ((size_t)b * CCH) * NTOK;
  float* ob = out + ((size_t)b * CCH) * NTOK;
#pragma unroll
  for (int mi = 0; mi < 4; ++mi)
#pragma unroll
    for (int j = 0; j < 4; ++j) {
      int o = m0 + wr * 64 + mi * 16 + lk * 4 + j;
      float cv = cvec[b * CCH + o];
      size_t rowoff = (size_t)o * NTOK;
#pragma unroll
      for (int ni = 0; ni < 4; ++ni) {
        int n = n0 + wc * 64 + ni * 16 + lr;
        size_t idx = rowoff + n;
        float xvv = __builtin_nontemporal_load(&xb[idx]);   // read-once, skip L2 fill
        __builtin_nontemporal_store(xvv + acc[mi][ni][j] + cv, &ob[idx]);  // never re-read
      }
    }
}

extern "C" void kernel_launch(void* const* d_in, const int* in_sizes, int n_in,
                              void* d_out, int out_size, void* d_ws, size_t ws_size,
                              hipStream_t stream) {
  const float* x    = (const float*)d_in[0];
  const float* gw   = (const float*)d_in[1];
  const float* gb   = (const float*)d_in[2];
  const float* qkvw = (const float*)d_in[3];
  const float* qkvb = (const float*)d_in[4];
  const float* outw = (const float*)d_in[5];
  const float* outb = (const float*)d_in[6];
  int B = in_sizes[0] / (CCH * NTOK);   // 4

  char* ws = (char*)d_ws;
  size_t off = 0;
  f16* H    = (f16*)(ws + off);   off += (size_t)B * CCH * NTOK * 2;   // 64 MiB
  f16* Ht   = (f16*)(ws + off);   off += (size_t)B * NTOK * CCH * 2;   // 64 MiB
  float* G  = (float*)(ws + off); off += (size_t)B * CCH * CCH * 4;    // 4 MiB
  float* T1 = (float*)(ws + off); off += (size_t)B * CCH * CCH * 4;    // 4 MiB
  float* R  = (float*)(ws + off); off += (size_t)B * CCH * CCH * 4;    // 4 MiB
  f16* M16  = (f16*)(ws + off);   off += (size_t)B * CCH * CCH * 2;    // 2 MiB
  float* P  = (float*)(ws + off); off += (size_t)B * NHEAD * 64 * 64 * 4;  // 512 KiB
  float* uvec  = (float*)(ws + off); off += (size_t)B * 1024 * 4;
  float* pbv   = (float*)(ws + off); off += (size_t)B * CCH * 4;
  float* cvec  = (float*)(ws + off); off += (size_t)B * CCH * 4;
  // zero-init region: stats, svec, L (contiguous -> single memset)
  float* stats = (float*)(ws + off); off += (size_t)B * 8 * 2 * 4;
  float* svec  = (float*)(ws + off); off += (size_t)B * CCH * 4;
  float* L     = (float*)(ws + off); off += (size_t)B * NHEAD * 64 * 64 * 4;  // 512 KiB
  size_t zbytes = (size_t)(B * 8 * 2 + B * CCH + B * NHEAD * 64 * 64) * 4;

  hipMemsetAsync(G, 0, (size_t)B * CCH * CCH * 4, stream);
  hipMemsetAsync(stats, 0, zbytes, stream);

  k_stats<<<dim3(32, B * 8), 256, 0, stream>>>(x, stats);
  k_gnorm<<<dim3(64, 8, B), 256, 0, stream>>>(x, gw, gb, stats, H, Ht, svec);
  k_syrk<<<dim3(10, SPLITS, B), 256, 0, stream>>>(H, G);
  k_symm<<<dim3(24, B), 256, 0, stream>>>(G);
  k_sgemm512<false><<<dim3(8, 8, B), 256, 0, stream>>>(qkvw, G, T1,
                                                       (size_t)CCH * CCH, (size_t)CCH * CCH);
  k_uvec<<<dim3(16, B), 256, 0, stream>>>(qkvw, svec, uvec);
  k_logits<<<dim3(8, NHEAD, B), 256, 0, stream>>>(T1, qkvw, L);
  k_softmax<<<dim3(B * NHEAD), 64, 0, stream>>>(L, uvec, qkvb, P, pbv);
  k_pv<<<dim3(8, NHEAD, B), 256, 0, stream>>>(P, qkvw, R);
  k_sgemm512<true><<<dim3(8, 8, B), 256, 0, stream>>>(outw, R, M16,
                                                      (size_t)CCH * CCH, (size_t)CCH * CCH);
  k_cvec<<<dim3(8, B), 256, 0, stream>>>(outw, outb, pbv, cvec);
  k_out<<<dim3(128, 4, B), 256, 0, stream>>>(M16, Ht, x, cvec, (float*)d_out);
}

// Round 13
// 359.867 us; speedup vs baseline: 1.1441x; 1.1441x over previous
//
#include <hip/hip_runtime.h>
#include <hip/hip_fp16.h>

// AttentionBlock3D: channel attention. B=4, C=512, N=T*H*W=16384, 8 heads, d=64.
// Algebraic reduction: result = x + M*H + c, with
//   G = H H^T (per batch, SYMMETRIC -> upper tiles only + k_symm mirror+cast),
//   logits = scale*(Wq G Wk^T + rank-1), P = softmax per head,
//   M = out_w * blockdiag(P) * Wv, c = out_w * blockdiag(P) * bv + out_b.
//
// MFMA kernel geometry: LOCKED at measured-best (R9):
//   BK=64 (128B rows, 8x16B slots, XOR-swizzle slot^(row&7) => 0 bank conflicts),
//   single LDS buffer (32 KiB), 2 barriers per K-step, __launch_bounds__(256,2).
//   Measured dead ends on this structure: lb(256,4) -39% (R8); BK=32 conflicts
//   (R7); 64KB dbuf (R6,R11), counted-vmcnt (R11), x-prefetch (R10),
//   nt-epilogue (R12, +13us write-amp) all neutral-to-worse. k_out plateau 84us.
// R13: both fp32 512^3 GEMMs -> fp16 MFMA (k_hgemm512, same proven geometry).
//   G16 stored as fp16(G - 16384*I); exact rank-shift restored in epilogue via
//   fp32 Wq (kills fp16 ulp=16 diag quantization). k_pv emits transposed fp16 R.

#define CCH 512
#define NTOK 16384
#define NHEAD 8

typedef _Float16 f16;
typedef _Float16 f16x8 __attribute__((ext_vector_type(8)));
typedef float f32x4 __attribute__((ext_vector_type(4)));

__device__ __forceinline__ void g2l16(const void* g, void* l) {
  __builtin_amdgcn_global_load_lds((const __attribute__((address_space(1))) void*)g,
                                   (__attribute__((address_space(3))) void*)l,
                                   16, 0, 0);
}

// ---------------- K0: fp32 -> fp16 cast (vectorized) ----------------
__global__ __launch_bounds__(256) void k_cast(const float* __restrict__ src,
                                              f16* __restrict__ dst, int n4) {
  int i = blockIdx.x * 256 + threadIdx.x;
  if (i < n4) {
    float4 v = *(const float4*)&src[i * 4];
    f16 h[4] __attribute__((aligned(8)));
    h[0] = (f16)v.x; h[1] = (f16)v.y; h[2] = (f16)v.z; h[3] = (f16)v.w;
    *(uint2*)&dst[i * 4] = *(const uint2*)h;
  }
}

// ---------------- K1: GroupNorm stats (sum, sumsq) per (b, group) ----------------
__global__ __launch_bounds__(256) void k_stats(const float* __restrict__ x,
                                               float* __restrict__ stats) {
  int bg = blockIdx.y;          // b*8 + g  (group region is contiguous: 64 rows * NTOK)
  int chunk = blockIdx.x;       // 0..31
  const float4* p = (const float4*)(x + (size_t)bg * (64ull * NTOK)) + (size_t)chunk * 8192;
  float s = 0.f, q = 0.f;
  for (int i = threadIdx.x; i < 8192; i += 256) {
    float4 v = p[i];
    s += v.x + v.y + v.z + v.w;
    q += v.x * v.x + v.y * v.y + v.z * v.z + v.w * v.w;
  }
  for (int off = 32; off; off >>= 1) { s += __shfl_down(s, off); q += __shfl_down(q, off); }
  __shared__ float ls[4], lq[4];
  int wid = threadIdx.x >> 6, lane = threadIdx.x & 63;
  if (lane == 0) { ls[wid] = s; lq[wid] = q; }
  __syncthreads();
  if (threadIdx.x == 0) {
    atomicAdd(&stats[bg * 2 + 0], ls[0] + ls[1] + ls[2] + ls[3]);
    atomicAdd(&stats[bg * 2 + 1], lq[0] + lq[1] + lq[2] + lq[3]);
  }
}

// ---------------- K2: normalize -> H (fp16, [b][c][n]) and Ht (fp16, [b][n][c]), s = H*1 ----
__global__ __launch_bounds__(256) void k_gnorm(const float* __restrict__ x,
                                               const float* __restrict__ gw,
                                               const float* __restrict__ gb,
                                               const float* __restrict__ stats,
                                               f16* __restrict__ H, f16* __restrict__ Ht,
                                               float* __restrict__ svec) {
  int nc = blockIdx.x;   // n chunk (256 tokens)
  int cg = blockIdx.y;   // channel group (64 ch) == GN group
  int b = blockIdx.z;
  int t = threadIdx.x;
  __shared__ f16 T2[64][260];     // [c_local][n_local], 260-half rows (520B: bank stride 2)
  __shared__ float svp[4][64];
  float sum = stats[(b * 8 + cg) * 2], sq = stats[(b * 8 + cg) * 2 + 1];
  const float inv = 1.f / (64.f * (float)NTOK);
  float mean = sum * inv;
  float var = fmaxf(sq * inv - mean * mean, 0.f);
  float rsig = rsqrtf(var + 1e-5f);
  int c0 = cg * 64, n0 = nc * 256;
  int tq = t & 63, rr0 = t >> 6;       // lane owns 4 consecutive tokens; wave owns row set
#pragma unroll
  for (int it = 0; it < 16; ++it) {
    int r = it * 4 + rr0;
    int c = c0 + r;
    float a = gw[c] * rsig;
    float bb = gb[c] - mean * a;
    size_t idx = ((size_t)(b * CCH + c)) * NTOK + n0 + tq * 4;
    float4 xv = *(const float4*)&x[idx];
    f16 hh[4] __attribute__((aligned(8)));
    hh[0] = (f16)(xv.x * a + bb);
    hh[1] = (f16)(xv.y * a + bb);
    hh[2] = (f16)(xv.z * a + bb);
    hh[3] = (f16)(xv.w * a + bb);
    *(uint2*)&H[idx] = *(const uint2*)hh;          // 8B store
    *(uint2*)&T2[r][tq * 4] = *(const uint2*)hh;   // 8B LDS write, 2-bank lane stride
  }
  __syncthreads();
  {  // svec partials: 4 quarter-sums per channel, then combine
    int c = t & 63, q = t >> 6;
    float acc = 0.f;
#pragma unroll
    for (int j = 0; j < 64; ++j) acc += (float)T2[c][q * 64 + j];
    svp[q][c] = acc;
  }
  __syncthreads();
  if (t < 64) {
    atomicAdd(&svec[b * CCH + c0 + t],
              svp[0][t] + svp[1][t] + svp[2][t] + svp[3][t]);
  }
  int s8 = t & 7, nl = t >> 3;        // transpose write-out: 8 threads per Ht row
#pragma unroll
  for (int it = 0; it < 8; ++it) {
    int n = it * 32 + nl;
    f16 g[8] __attribute__((aligned(16)));
#pragma unroll
    for (int j = 0; j < 8; ++j) g[j] = T2[s8 * 8 + j][n];
    *(uint4*)&Ht[((size_t)b * NTOK + n0 + n) * CCH + c0 + s8 * 8] = *(const uint4*)g;
  }
}

// ---------------- K3: G = H H^T, upper tiles, split-K=16, BK=64 single-buf (32KB) ----
#define SPLITS 16
__global__ __launch_bounds__(256, 2) void k_syrk(const f16* __restrict__ H,
                                                 float* __restrict__ G) {
  // 10 upper-triangle tiles of 128x128 over the 512x512 output
  const int TI[10] = {0, 0, 0, 0, 1, 1, 1, 2, 2, 3};
  const int TJ[10] = {0, 1, 2, 3, 1, 2, 3, 2, 3, 3};
  int tile = blockIdx.x;
  int split = blockIdx.y;
  int b = blockIdx.z;
  int ii = TI[tile], jj = TJ[tile];
  int m0 = ii * 128, n0 = jj * 128;
  int t = threadIdx.x, lane = t & 63, wid = t >> 6;
  int wr = wid >> 1, wc = wid & 1;
  __shared__ __align__(16) f16 sA[128 * 64];
  __shared__ __align__(16) f16 sB[128 * 64];
  const f16* Hb = H + (size_t)b * CCH * NTOK;
  int k0 = split * (NTOK / SPLITS);     // 1024 per split
  f32x4 acc[4][4] = {};
  int ldsrow = wid * 8 + (lane >> 3);   // 128B rows: 8 lanes/row
  int slot = lane & 7;                  // 16B slot within row
  int lr = lane & 15, lk = lane >> 4;

  const int NS = (NTOK / SPLITS) / 64;  // 16 K-steps of BK=64
  for (int ks = 0; ks < NS; ++ks) {
    int kk0 = k0 + ks * 64;
    __syncthreads();
#pragma unroll
    for (int i = 0; i < 4; ++i) {
      int row = ldsrow + i * 32;
      int cA = ((slot ^ (row & 7)) * 8);  // pre-swizzled global source column
      g2l16(Hb + (size_t)(m0 + row) * NTOK + kk0 + cA, &sA[i * 2048 + wid * 512]);
      g2l16(Hb + (size_t)(n0 + row) * NTOK + kk0 + cA, &sB[i * 2048 + wid * 512]);
    }
    asm volatile("s_waitcnt vmcnt(0)" ::: "memory");
    __syncthreads();
#pragma unroll
    for (int kk = 0; kk < 2; ++kk) {
      f16x8 af[4], bf[4];
#pragma unroll
      for (int mi = 0; mi < 4; ++mi) {
        int row = wr * 64 + mi * 16 + lr;
        int ks8 = (kk * 4 + lk) ^ (row & 7);
        af[mi] = *(const f16x8*)&sA[row * 64 + ks8 * 8];
      }
#pragma unroll
      for (int ni = 0; ni < 4; ++ni) {
        int row = wc * 64 + ni * 16 + lr;
        int ks8 = (kk * 4 + lk) ^ (row & 7);
        bf[ni] = *(const f16x8*)&sB[row * 64 + ks8 * 8];
      }
#pragma unroll
      for (int mi = 0; mi < 4; ++mi)
#pragma unroll
        for (int ni = 0; ni < 4; ++ni)
          acc[mi][ni] = __builtin_amdgcn_mfma_f32_16x16x32_f16(af[mi], bf[ni], acc[mi][ni], 0, 0, 0);
    }
  }

  float* Gb = G + (size_t)b * CCH * CCH;
#pragma unroll
  for (int mi = 0; mi < 4; ++mi)
#pragma unroll
    for (int j = 0; j < 4; ++j) {
      int rr2 = m0 + wr * 64 + mi * 16 + lk * 4 + j;
#pragma unroll
      for (int ni = 0; ni < 4; ++ni) {
        int cc = n0 + wc * 64 + ni * 16 + lr;
        atomicAdd(&Gb[(size_t)rr2 * CCH + cc], acc[mi][ni][j]);   // coalesced rows only
      }
    }
}

// ---------------- K3b: mirror upper off-diag tiles + cast full G -> G16 ------------
// G16 = fp16(G - 16384*I): diag shift keeps fp16 ulp small (diag~16384 -> ulp 16);
// the exact 16384*Wq rank-shift is restored in k_hgemm512's fp32 epilogue.
__global__ __launch_bounds__(256) void k_symm(float* __restrict__ G,
                                              f16* __restrict__ G16) {
  const int TI6[6] = {0, 0, 0, 1, 1, 2};
  const int TJ6[6] = {1, 2, 3, 2, 3, 3};
  int bx = blockIdx.x;               // [0,24): off-diag mirror+cast; [24,40): diag cast
  int b = blockIdx.y;
  float* Gb = G + (size_t)b * CCH * CCH;
  f16* Gh = G16 + (size_t)b * CCH * CCH;
  __shared__ float s[64][65];
  int t = threadIdx.x;
  int r = t >> 2, cg = (t & 3) * 16;
  int ib, jb;
  bool mirror = bx < 24;
  if (mirror) {
    int t6 = bx >> 2, sub = bx & 3;
    ib = TI6[t6] * 2 + (sub >> 1); jb = TJ6[t6] * 2 + (sub & 1);
  } else {
    int idx = bx - 24; int dt = idx >> 2, sub = idx & 3;
    ib = dt * 2 + (sub >> 1); jb = dt * 2 + (sub & 1);
  }
  int grow = ib * 64 + r, gcol0 = jb * 64 + cg;
  const float* src = &Gb[(size_t)grow * CCH + gcol0];
  f16 hv[16] __attribute__((aligned(16)));
#pragma unroll
  for (int k = 0; k < 4; ++k) {
    float4 v = *(const float4*)(src + k * 4);
    if (mirror) {
      s[r][cg + k * 4 + 0] = v.x; s[r][cg + k * 4 + 1] = v.y;
      s[r][cg + k * 4 + 2] = v.z; s[r][cg + k * 4 + 3] = v.w;
    }
    hv[k * 4 + 0] = (f16)(v.x - ((grow == gcol0 + k * 4 + 0) ? 16384.f : 0.f));
    hv[k * 4 + 1] = (f16)(v.y - ((grow == gcol0 + k * 4 + 1) ? 16384.f : 0.f));
    hv[k * 4 + 2] = (f16)(v.z - ((grow == gcol0 + k * 4 + 2) ? 16384.f : 0.f));
    hv[k * 4 + 3] = (f16)(v.w - ((grow == gcol0 + k * 4 + 3) ? 16384.f : 0.f));
  }
  f16* d16 = &Gh[(size_t)grow * CCH + gcol0];
  *(uint4*)&d16[0] = ((const uint4*)hv)[0];
  *(uint4*)&d16[8] = ((const uint4*)hv)[1];
  if (mirror) {
    __syncthreads();
    float* dst = &Gb[(size_t)(jb * 64 + r) * CCH + ib * 64 + cg];
    f16 hw[16] __attribute__((aligned(16)));
#pragma unroll
    for (int k = 0; k < 4; ++k) {
      float4 v;
      v.x = s[cg + k * 4 + 0][r]; v.y = s[cg + k * 4 + 1][r];
      v.z = s[cg + k * 4 + 2][r]; v.w = s[cg + k * 4 + 3][r];
      *(float4*)(dst + k * 4) = v;
      hw[k * 4 + 0] = (f16)v.x; hw[k * 4 + 1] = (f16)v.y;
      hw[k * 4 + 2] = (f16)v.z; hw[k * 4 + 3] = (f16)v.w;   // off-diag: no shift
    }
    f16* m16 = &Gh[(size_t)(jb * 64 + r) * CCH + ib * 64 + cg];
    *(uint4*)&m16[0] = ((const uint4*)hw)[0];
    *(uint4*)&m16[8] = ((const uint4*)hw)[1];
  }
}

// ---------------- K4: fp16 MFMA 512^3 GEMM: C[b] = A16 @ Bt16[b]^T ----------------
// A16 [512][512] shared across b; Bt16 is B TRANSPOSED ([n][k], k contiguous).
// CORR (T1 path): C += 16384 * corr[m][n] (fp32) -- restores G's diag shift.
template <bool HALF_OUT, bool CORR>
__global__ __launch_bounds__(256, 2) void k_hgemm512(const f16* __restrict__ A16,
                                                     const f16* __restrict__ Bt16,
                                                     void* __restrict__ Cv,
                                                     const float* __restrict__ corr) {
  int n0 = blockIdx.x * 128, m0 = blockIdx.y * 128, b = blockIdx.z;
  int t = threadIdx.x, lane = t & 63, wid = t >> 6;
  int wr = wid >> 1, wc = wid & 1;
  __shared__ __align__(16) f16 sA[128 * 64];
  __shared__ __align__(16) f16 sB[128 * 64];
  const f16* A = A16;
  const f16* Bp = Bt16 + (size_t)b * CCH * CCH;
  f32x4 acc[4][4] = {};
  int ldsrow = wid * 8 + (lane >> 3);
  int slot = lane & 7;
  int lr = lane & 15, lk = lane >> 4;
  for (int ks = 0; ks < 8; ++ks) {
    int kk0 = ks * 64;
    __syncthreads();
#pragma unroll
    for (int i = 0; i < 4; ++i) {
      int row = ldsrow + i * 32;
      int cA = ((slot ^ (row & 7)) * 8);
      g2l16(A + (size_t)(m0 + row) * CCH + kk0 + cA, &sA[i * 2048 + wid * 512]);
      g2l16(Bp + (size_t)(n0 + row) * CCH + kk0 + cA, &sB[i * 2048 + wid * 512]);
    }
    asm volatile("s_waitcnt vmcnt(0)" ::: "memory");
    __syncthreads();
#pragma unroll
    for (int kk = 0; kk < 2; ++kk) {
      f16x8 af[4], bf[4];
#pragma unroll
      for (int mi = 0; mi < 4; ++mi) {
        int row = wr * 64 + mi * 16 + lr;
        int ks8 = (kk * 4 + lk) ^ (row & 7);
        af[mi] = *(const f16x8*)&sA[row * 64 + ks8 * 8];
      }
#pragma unroll
      for (int ni = 0; ni < 4; ++ni) {
        int row = wc * 64 + ni * 16 + lr;
        int ks8 = (kk * 4 + lk) ^ (row & 7);
        bf[ni] = *(const f16x8*)&sB[row * 64 + ks8 * 8];
      }
#pragma unroll
      for (int mi = 0; mi < 4; ++mi)
#pragma unroll
        for (int ni = 0; ni < 4; ++ni)
          acc[mi][ni] = __builtin_amdgcn_mfma_f32_16x16x32_f16(af[mi], bf[ni], acc[mi][ni], 0, 0, 0);
    }
  }
#pragma unroll
  for (int mi = 0; mi < 4; ++mi)
#pragma unroll
    for (int j = 0; j < 4; ++j) {
      int o = m0 + wr * 64 + mi * 16 + lk * 4 + j;
#pragma unroll
      for (int ni = 0; ni < 4; ++ni) {
        int n = n0 + wc * 64 + ni * 16 + lr;
        float v = acc[mi][ni][j];
        if constexpr (CORR) v += 16384.f * corr[(size_t)o * CCH + n];
        if constexpr (HALF_OUT)
          ((f16*)Cv)[(size_t)b * CCH * CCH + (size_t)o * CCH + n] = (f16)v;
        else
          ((float*)Cv)[(size_t)b * CCH * CCH + (size_t)o * CCH + n] = v;
      }
    }
}

// ---------------- K4b-1: uvec[b][0:512]=Wq@s, [512:1024]=Wk@s (4 lanes/output) ----
__global__ __launch_bounds__(256) void k_uvec(const float* __restrict__ qkvw,
                                              const float* __restrict__ svec,
                                              float* __restrict__ uvec) {
  int o = blockIdx.x * 64 + (threadIdx.x >> 2);   // grid.x = 16
  int l = threadIdx.x & 3;
  int b = blockIdx.y;
  __shared__ float ss[512];
  for (int i = threadIdx.x; i < 512; i += 256) ss[i] = svec[b * CCH + i];
  __syncthreads();
  const float* wr_ = qkvw + (size_t)o * CCH + l * 128;
  const float* sp = ss + l * 128;
  float a = 0.f;
#pragma unroll
  for (int i = 0; i < 32; ++i) {
    float4 w = *(const float4*)&wr_[i * 4];
    a += w.x * sp[i * 4] + w.y * sp[i * 4 + 1] + w.z * sp[i * 4 + 2] + w.w * sp[i * 4 + 3];
  }
  a += __shfl_down(a, 2);
  a += __shfl_down(a, 1);
  if (l == 0) uvec[b * 1024 + o] = a;
}

// ---------------- K4b-2: L[b,h] += T1_h[64xK-chunk] @ Wk_h^T (split-K, atomics) ----
__global__ __launch_bounds__(256) void k_logits(const float* __restrict__ T1,
                                                const float* __restrict__ qkvw,
                                                float* __restrict__ L) {
  int kc = blockIdx.x;     // 8 chunks of 64 k
  int h = blockIdx.y, b = blockIdx.z;
  int t = threadIdx.x;
  int h64 = h * 64, k0 = kc * 64;
  __shared__ float sT[64][68];   // [d][k]
  __shared__ float sW[64][68];   // [k][e]
#pragma unroll
  for (int i = 0; i < 16; ++i) {
    int idx = i * 256 + t;
    int r = idx >> 6, c = idx & 63;
    sT[r][c] = T1[((size_t)b * CCH + h64 + r) * CCH + k0 + c];
    sW[c][r] = qkvw[(size_t)(512 + h64 + r) * CCH + k0 + c];
  }
  __syncthreads();
  int d = t >> 2, eg = (t & 3) * 16;
  float acc[16] = {};
  for (int k = 0; k < 64; ++k) {
    float a = sT[d][k];
    float4 w0 = *(const float4*)&sW[k][eg];
    float4 w1 = *(const float4*)&sW[k][eg + 4];
    float4 w2 = *(const float4*)&sW[k][eg + 8];
    float4 w3 = *(const float4*)&sW[k][eg + 12];
    acc[0] += a * w0.x;  acc[1] += a * w0.y;  acc[2] += a * w0.z;  acc[3] += a * w0.w;
    acc[4] += a * w1.x;  acc[5] += a * w1.y;  acc[6] += a * w1.z;  acc[7] += a * w1.w;
    acc[8] += a * w2.x;  acc[9] += a * w2.y;  acc[10] += a * w2.z; acc[11] += a * w2.w;
    acc[12] += a * w3.x; acc[13] += a * w3.y; acc[14] += a * w3.z; acc[15] += a * w3.w;
  }
  float* Lrow = &L[(((size_t)b * NHEAD + h) * 64 + d) * 64 + eg];
#pragma unroll
  for (int i = 0; i < 16; ++i) atomicAdd(&Lrow[i], acc[i]);
}

// ---------------- K4b-3: softmax rows + rank-1 bias terms -> P, pbv ----------------
__global__ __launch_bounds__(64) void k_softmax(const float* __restrict__ L,
                                                const float* __restrict__ uvec,
                                                const float* __restrict__ qkvb,
                                                float* __restrict__ P,
                                                float* __restrict__ pbv) {
  int bh = blockIdx.x;           // b*8 + h
  int b = bh >> 3, h = bh & 7;
  int d = threadIdx.x;           // 0..63
  int h64 = h * 64;
  __shared__ float sbk[64], sbv[64], suk[64];
  sbk[d] = qkvb[512 + h64 + d];
  sbv[d] = qkvb[1024 + h64 + d];
  suk[d] = uvec[b * 1024 + 512 + h64 + d];
  __syncthreads();
  float uq = uvec[b * 1024 + h64 + d];
  float bq = qkvb[h64 + d];
  float l[64];
  const float* Lr = &L[((size_t)bh * 64 + d) * 64];
  float m = -1e30f;
#pragma unroll
  for (int e = 0; e < 64; ++e) {
    float v = (Lr[e] + uq * sbk[e] + bq * suk[e] + 16384.f * bq * sbk[e]) * 0.125f;
    l[e] = v;
    m = fmaxf(m, v);
  }
  float sum = 0.f;
#pragma unroll
  for (int e = 0; e < 64; ++e) { float p = expf(l[e] - m); l[e] = p; sum += p; }
  float r = 1.f / sum, pb = 0.f;
  float* Pr = &P[((size_t)bh * 64 + d) * 64];
#pragma unroll
  for (int e = 0; e < 64; ++e) { float p = l[e] * r; Pr[e] = p; pb += p * sbv[e]; }
  pbv[b * CCH + h64 + d] = pb;
}

// ---------------- K4b-4: Rt16[b, c, h64+d] = sum_e P[b,h,d,e] Wv[h64+e][c] --------
// Transposed fp16 output so the M-GEMM's B-operand is [n][k]-contiguous.
__global__ __launch_bounds__(256) void k_pv(const float* __restrict__ P,
                                            const float* __restrict__ qkvw,
                                            f16* __restrict__ Rt16) {
  int ct = blockIdx.x;     // 8 c-tiles of 64
  int h = blockIdx.y, b = blockIdx.z;
  int t = threadIdx.x;
  int h64 = h * 64, c0 = ct * 64;
  __shared__ float sPt[64][68];  // [e][d] (P transposed)
  __shared__ float sW[64][68];   // [e][c]
#pragma unroll
  for (int i = 0; i < 16; ++i) {
    int idx = i * 256 + t;
    int rr = idx >> 6, c = idx & 63;
    sPt[c][rr] = P[(((size_t)b * NHEAD + h) * 64 + rr) * 64 + c];  // sPt[e][d]=P[d][e]
    sW[rr][c] = qkvw[(size_t)(1024 + h64 + rr) * CCH + c0 + c];
  }
  __syncthreads();
  int cl = t >> 2, dg = (t & 3) * 16;
  float acc[16] = {};
  for (int e = 0; e < 64; ++e) {
    float w = sW[e][cl];
    float4 p0 = *(const float4*)&sPt[e][dg];
    float4 p1 = *(const float4*)&sPt[e][dg + 4];
    float4 p2 = *(const float4*)&sPt[e][dg + 8];
    float4 p3 = *(const float4*)&sPt[e][dg + 12];
    acc[0]  += w * p0.x; acc[1]  += w * p0.y; acc[2]  += w * p0.z; acc[3]  += w * p0.w;
    acc[4]  += w * p1.x; acc[5]  += w * p1.y; acc[6]  += w * p1.z; acc[7]  += w * p1.w;
    acc[8]  += w * p2.x; acc[9]  += w * p2.y; acc[10] += w * p2.z; acc[11] += w * p2.w;
    acc[12] += w * p3.x; acc[13] += w * p3.y; acc[14] += w * p3.z; acc[15] += w * p3.w;
  }
  f16 hv[16] __attribute__((aligned(16)));
#pragma unroll
  for (int i = 0; i < 16; ++i) hv[i] = (f16)acc[i];
  f16* dst = &Rt16[((size_t)b * CCH + c0 + cl) * CCH + h64 + dg];
  *(uint4*)&dst[0] = ((const uint4*)hv)[0];
  *(uint4*)&dst[8] = ((const uint4*)hv)[1];
}

// ---------------- K4d: cvec = out_w @ pbv + out_b (4 lanes/output) ----------------
__global__ __launch_bounds__(256) void k_cvec(const float* __restrict__ outw,
                                              const float* __restrict__ outb,
                                              const float* __restrict__ pbv,
                                              float* __restrict__ cvec) {
  int o = blockIdx.x * 64 + (threadIdx.x >> 2);   // grid.x = 8
  int l = threadIdx.x & 3;
  int b = blockIdx.y;
  __shared__ float sp[512];
  for (int i = threadIdx.x; i < 512; i += 256) sp[i] = pbv[b * CCH + i];
  __syncthreads();
  const float* wr_ = outw + (size_t)o * CCH + l * 128;
  const float* spp = sp + l * 128;
  float a = 0.f;
#pragma unroll
  for (int i = 0; i < 32; ++i) {
    float4 w = *(const float4*)&wr_[i * 4];
    a += w.x * spp[i * 4] + w.y * spp[i * 4 + 1] + w.z * spp[i * 4 + 2] + w.w * spp[i * 4 + 3];
  }
  a += __shfl_down(a, 2);
  a += __shfl_down(a, 1);
  if (l == 0) cvec[b * CCH + o] = a + outb[o];
}

// ---------------- K5: out = x + M16 @ H + cvec (fp16 MFMA, BK=64 single-buf) -------
__global__ __launch_bounds__(256, 2) void k_out(const f16* __restrict__ M16,
                                                const f16* __restrict__ Ht,
                                                const float* __restrict__ x,
                                                const float* __restrict__ cvec,
                                                float* __restrict__ out) {
  int nt = blockIdx.x;   // 128 n-tiles
  int mt = blockIdx.y;   // 4 o-tiles
  int b = blockIdx.z;
  int m0 = mt * 128, n0 = nt * 128;
  int t = threadIdx.x, lane = t & 63, wid = t >> 6;
  int wr = wid >> 1, wc = wid & 1;
  __shared__ __align__(16) f16 sA[128 * 64];
  __shared__ __align__(16) f16 sB[128 * 64];
  const f16* A = M16 + (size_t)b * CCH * CCH;
  const f16* Bp = Ht + (size_t)b * NTOK * CCH;
  f32x4 acc[4][4] = {};
  int ldsrow = wid * 8 + (lane >> 3);
  int slot = lane & 7;
  int lr = lane & 15, lk = lane >> 4;
  for (int ks = 0; ks < 8; ++ks) {
    int kk0 = ks * 64;
    __syncthreads();
#pragma unroll
    for (int i = 0; i < 4; ++i) {
      int row = ldsrow + i * 32;
      int cA = ((slot ^ (row & 7)) * 8);
      g2l16(A + (size_t)(m0 + row) * CCH + kk0 + cA, &sA[i * 2048 + wid * 512]);
      g2l16(Bp + (size_t)(n0 + row) * CCH + kk0 + cA, &sB[i * 2048 + wid * 512]);
    }
    asm volatile("s_waitcnt vmcnt(0)" ::: "memory");
    __syncthreads();
#pragma unroll
    for (int kk = 0; kk < 2; ++kk) {
      f16x8 af[4], bf[4];
#pragma unroll
      for (int mi = 0; mi < 4; ++mi) {
        int row = wr * 64 + mi * 16 + lr;
        int ks8 = (kk * 4 + lk) ^ (row & 7);
        af[mi] = *(const f16x8*)&sA[row * 64 + ks8 * 8];
      }
#pragma unroll
      for (int ni = 0; ni < 4; ++ni) {
        int row = wc * 64 + ni * 16 + lr;
        int ks8 = (kk * 4 + lk) ^ (row & 7);
        bf[ni] = *(const f16x8*)&sB[row * 64 + ks8 * 8];
      }
#pragma unroll
      for (int mi = 0; mi < 4; ++mi)
#pragma unroll
        for (int ni = 0; ni < 4; ++ni)
          acc[mi][ni] = __builtin_amdgcn_mfma_f32_16x16x32_f16(af[mi], bf[ni], acc[mi][ni], 0, 0, 0);
    }
  }

  const float* xb = x + ((size_t)b * CCH) * NTOK;
  float* ob = out + ((size_t)b * CCH) * NTOK;
#pragma unroll
  for (int mi = 0; mi < 4; ++mi)
#pragma unroll
    for (int j = 0; j < 4; ++j) {
      int o = m0 + wr * 64 + mi * 16 + lk * 4 + j;
      float cv = cvec[b * CCH + o];
      size_t rowoff = (size_t)o * NTOK;
#pragma unroll
      for (int ni = 0; ni < 4; ++ni) {
        int n = n0 + wc * 64 + ni * 16 + lr;
        size_t idx = rowoff + n;
        ob[idx] = xb[idx] + acc[mi][ni][j] + cv;
      }
    }
}

extern "C" void kernel_launch(void* const* d_in, const int* in_sizes, int n_in,
                              void* d_out, int out_size, void* d_ws, size_t ws_size,
                              hipStream_t stream) {
  const float* x    = (const float*)d_in[0];
  const float* gw   = (const float*)d_in[1];
  const float* gb   = (const float*)d_in[2];
  const float* qkvw = (const float*)d_in[3];
  const float* qkvb = (const float*)d_in[4];
  const float* outw = (const float*)d_in[5];
  const float* outb = (const float*)d_in[6];
  int B = in_sizes[0] / (CCH * NTOK);   // 4

  char* ws = (char*)d_ws;
  size_t off = 0;
  f16* H    = (f16*)(ws + off);   off += (size_t)B * CCH * NTOK * 2;   // 64 MiB
  f16* Ht   = (f16*)(ws + off);   off += (size_t)B * NTOK * CCH * 2;   // 64 MiB
  float* G  = (float*)(ws + off); off += (size_t)B * CCH * CCH * 4;    // 4 MiB
  float* T1 = (float*)(ws + off); off += (size_t)B * CCH * CCH * 4;    // 4 MiB
  f16* G16  = (f16*)(ws + off);   off += (size_t)B * CCH * CCH * 2;    // 2 MiB
  f16* Rt16 = (f16*)(ws + off);   off += (size_t)B * CCH * CCH * 2;    // 2 MiB
  f16* M16  = (f16*)(ws + off);   off += (size_t)B * CCH * CCH * 2;    // 2 MiB
  f16* Wq16 = (f16*)(ws + off);   off += (size_t)CCH * CCH * 2;        // 0.5 MiB
  f16* Ow16 = (f16*)(ws + off);   off += (size_t)CCH * CCH * 2;        // 0.5 MiB
  float* P  = (float*)(ws + off); off += (size_t)B * NHEAD * 64 * 64 * 4;  // 512 KiB
  float* uvec  = (float*)(ws + off); off += (size_t)B * 1024 * 4;
  float* pbv   = (float*)(ws + off); off += (size_t)B * CCH * 4;
  float* cvec  = (float*)(ws + off); off += (size_t)B * CCH * 4;
  // zero-init region: stats, svec, L (contiguous -> single memset)
  float* stats = (float*)(ws + off); off += (size_t)B * 8 * 2 * 4;
  float* svec  = (float*)(ws + off); off += (size_t)B * CCH * 4;
  float* L     = (float*)(ws + off); off += (size_t)B * NHEAD * 64 * 64 * 4;  // 512 KiB
  size_t zbytes = (size_t)(B * 8 * 2 + B * CCH + B * NHEAD * 64 * 64) * 4;

  hipMemsetAsync(G, 0, (size_t)B * CCH * CCH * 4, stream);
  hipMemsetAsync(stats, 0, zbytes, stream);

  k_cast<<<dim3(CCH * CCH / 1024), 256, 0, stream>>>(qkvw, Wq16, CCH * CCH / 4);
  k_cast<<<dim3(CCH * CCH / 1024), 256, 0, stream>>>(outw, Ow16, CCH * CCH / 4);
  k_stats<<<dim3(32, B * 8), 256, 0, stream>>>(x, stats);
  k_gnorm<<<dim3(64, 8, B), 256, 0, stream>>>(x, gw, gb, stats, H, Ht, svec);
  k_syrk<<<dim3(10, SPLITS, B), 256, 0, stream>>>(H, G);
  k_symm<<<dim3(40, B), 256, 0, stream>>>(G, G16);
  // T1 = Wq @ G  (B-operand = G16 via symmetry; +16384*Wq fp32 correction)
  k_hgemm512<false, true><<<dim3(4, 4, B), 256, 0, stream>>>(Wq16, G16, T1, qkvw);
  k_uvec<<<dim3(16, B), 256, 0, stream>>>(qkvw, svec, uvec);
  k_logits<<<dim3(8, NHEAD, B), 256, 0, stream>>>(T1, qkvw, L);
  k_softmax<<<dim3(B * NHEAD), 64, 0, stream>>>(L, uvec, qkvb, P, pbv);
  k_pv<<<dim3(8, NHEAD, B), 256, 0, stream>>>(P, qkvw, Rt16);
  // M16 = out_w @ R  (B-operand = Rt16, already transposed)
  k_hgemm512<true, false><<<dim3(4, 4, B), 256, 0, stream>>>(Ow16, Rt16, M16, nullptr);
  k_cvec<<<dim3(8, B), 256, 0, stream>>>(outw, outb, pbv, cvec);
  k_out<<<dim3(128, 4, B), 256, 0, stream>>>(M16, Ht, x, cvec, (float*)d_out);
}

// Round 14
// 358.827 us; speedup vs baseline: 1.1474x; 1.0029x over previous
//
#include <hip/hip_runtime.h>
#include <hip/hip_fp16.h>

// AttentionBlock3D: channel attention. B=4, C=512, N=T*H*W=16384, 8 heads, d=64.
// Algebraic reduction: result = x + M*H + c, with
//   G = H H^T (per batch, SYMMETRIC -> upper tiles only + k_symm mirror+cast),
//   logits = scale*(Wq G Wk^T + rank-1), P = softmax per head,
//   M = out_w * blockdiag(P) * Wv, c = out_w * blockdiag(P) * bv + out_b.
//
// MFMA kernel geometry: LOCKED at measured-best (R9):
//   BK=64 (128B rows, 8x16B slots, XOR-swizzle slot^(row&7) => 0 bank conflicts),
//   single LDS buffer (32 KiB), 2 barriers per K-step, __launch_bounds__(256,2).
//   Measured dead ends: lb(256,4) -39% (R8); BK=32 conflicts (R7); 64KB dbuf
//   (R6,R11), counted-vmcnt (R11), x-prefetch (R10), nt-epilogue (R12) all
//   neutral-to-worse.
// R13: fp32 512^3 GEMMs -> fp16 MFMA; G16 = fp16(G - 16384*I) + exact fp32
//   rank-shift restore in epilogue. 393 -> 360us.
// R14: k_out computes the TRANSPOSED fragment (mfma(bf,af)) so each lane holds
//   4 consecutive-n outputs -> float4 x-load / float4 store epilogue (4x fewer
//   epilogue memory instructions, 4x bytes-in-flight). k_cast fused to 1 launch.

#define CCH 512
#define NTOK 16384
#define NHEAD 8

typedef _Float16 f16;
typedef _Float16 f16x8 __attribute__((ext_vector_type(8)));
typedef float f32x4 __attribute__((ext_vector_type(4)));

__device__ __forceinline__ void g2l16(const void* g, void* l) {
  __builtin_amdgcn_global_load_lds((const __attribute__((address_space(1))) void*)g,
                                   (__attribute__((address_space(3))) void*)l,
                                   16, 0, 0);
}

// ---------------- K0: fp32 -> fp16 cast, two matrices in one launch ----------------
__global__ __launch_bounds__(256) void k_cast2(const float* __restrict__ srcA,
                                               f16* __restrict__ dstA,
                                               const float* __restrict__ srcB,
                                               f16* __restrict__ dstB, int n4) {
  int i = blockIdx.x * 256 + threadIdx.x;
  const float* src = blockIdx.y ? srcB : srcA;
  f16* dst = blockIdx.y ? dstB : dstA;
  if (i < n4) {
    float4 v = *(const float4*)&src[i * 4];
    f16 h[4] __attribute__((aligned(8)));
    h[0] = (f16)v.x; h[1] = (f16)v.y; h[2] = (f16)v.z; h[3] = (f16)v.w;
    *(uint2*)&dst[i * 4] = *(const uint2*)h;
  }
}

// ---------------- K1: GroupNorm stats (sum, sumsq) per (b, group) ----------------
__global__ __launch_bounds__(256) void k_stats(const float* __restrict__ x,
                                               float* __restrict__ stats) {
  int bg = blockIdx.y;          // b*8 + g  (group region is contiguous: 64 rows * NTOK)
  int chunk = blockIdx.x;       // 0..31
  const float4* p = (const float4*)(x + (size_t)bg * (64ull * NTOK)) + (size_t)chunk * 8192;
  float s = 0.f, q = 0.f;
  for (int i = threadIdx.x; i < 8192; i += 256) {
    float4 v = p[i];
    s += v.x + v.y + v.z + v.w;
    q += v.x * v.x + v.y * v.y + v.z * v.z + v.w * v.w;
  }
  for (int off = 32; off; off >>= 1) { s += __shfl_down(s, off); q += __shfl_down(q, off); }
  __shared__ float ls[4], lq[4];
  int wid = threadIdx.x >> 6, lane = threadIdx.x & 63;
  if (lane == 0) { ls[wid] = s; lq[wid] = q; }
  __syncthreads();
  if (threadIdx.x == 0) {
    atomicAdd(&stats[bg * 2 + 0], ls[0] + ls[1] + ls[2] + ls[3]);
    atomicAdd(&stats[bg * 2 + 1], lq[0] + lq[1] + lq[2] + lq[3]);
  }
}

// ---------------- K2: normalize -> H (fp16, [b][c][n]) and Ht (fp16, [b][n][c]), s = H*1 ----
__global__ __launch_bounds__(256) void k_gnorm(const float* __restrict__ x,
                                               const float* __restrict__ gw,
                                               const float* __restrict__ gb,
                                               const float* __restrict__ stats,
                                               f16* __restrict__ H, f16* __restrict__ Ht,
                                               float* __restrict__ svec) {
  int nc = blockIdx.x;   // n chunk (256 tokens)
  int cg = blockIdx.y;   // channel group (64 ch) == GN group
  int b = blockIdx.z;
  int t = threadIdx.x;
  __shared__ f16 T2[64][260];     // [c_local][n_local], 260-half rows (520B: bank stride 2)
  __shared__ float svp[4][64];
  float sum = stats[(b * 8 + cg) * 2], sq = stats[(b * 8 + cg) * 2 + 1];
  const float inv = 1.f / (64.f * (float)NTOK);
  float mean = sum * inv;
  float var = fmaxf(sq * inv - mean * mean, 0.f);
  float rsig = rsqrtf(var + 1e-5f);
  int c0 = cg * 64, n0 = nc * 256;
  int tq = t & 63, rr0 = t >> 6;       // lane owns 4 consecutive tokens; wave owns row set
#pragma unroll
  for (int it = 0; it < 16; ++it) {
    int r = it * 4 + rr0;
    int c = c0 + r;
    float a = gw[c] * rsig;
    float bb = gb[c] - mean * a;
    size_t idx = ((size_t)(b * CCH + c)) * NTOK + n0 + tq * 4;
    float4 xv = *(const float4*)&x[idx];
    f16 hh[4] __attribute__((aligned(8)));
    hh[0] = (f16)(xv.x * a + bb);
    hh[1] = (f16)(xv.y * a + bb);
    hh[2] = (f16)(xv.z * a + bb);
    hh[3] = (f16)(xv.w * a + bb);
    *(uint2*)&H[idx] = *(const uint2*)hh;          // 8B store
    *(uint2*)&T2[r][tq * 4] = *(const uint2*)hh;   // 8B LDS write, 2-bank lane stride
  }
  __syncthreads();
  {  // svec partials: 4 quarter-sums per channel, then combine
    int c = t & 63, q = t >> 6;
    float acc = 0.f;
#pragma unroll
    for (int j = 0; j < 64; ++j) acc += (float)T2[c][q * 64 + j];
    svp[q][c] = acc;
  }
  __syncthreads();
  if (t < 64) {
    atomicAdd(&svec[b * CCH + c0 + t],
              svp[0][t] + svp[1][t] + svp[2][t] + svp[3][t]);
  }
  int s8 = t & 7, nl = t >> 3;        // transpose write-out: 8 threads per Ht row
#pragma unroll
  for (int it = 0; it < 8; ++it) {
    int n = it * 32 + nl;
    f16 g[8] __attribute__((aligned(16)));
#pragma unroll
    for (int j = 0; j < 8; ++j) g[j] = T2[s8 * 8 + j][n];
    *(uint4*)&Ht[((size_t)b * NTOK + n0 + n) * CCH + c0 + s8 * 8] = *(const uint4*)g;
  }
}

// ---------------- K3: G = H H^T, upper tiles, split-K=16, BK=64 single-buf (32KB) ----
#define SPLITS 16
__global__ __launch_bounds__(256, 2) void k_syrk(const f16* __restrict__ H,
                                                 float* __restrict__ G) {
  // 10 upper-triangle tiles of 128x128 over the 512x512 output
  const int TI[10] = {0, 0, 0, 0, 1, 1, 1, 2, 2, 3};
  const int TJ[10] = {0, 1, 2, 3, 1, 2, 3, 2, 3, 3};
  int tile = blockIdx.x;
  int split = blockIdx.y;
  int b = blockIdx.z;
  int ii = TI[tile], jj = TJ[tile];
  int m0 = ii * 128, n0 = jj * 128;
  int t = threadIdx.x, lane = t & 63, wid = t >> 6;
  int wr = wid >> 1, wc = wid & 1;
  __shared__ __align__(16) f16 sA[128 * 64];
  __shared__ __align__(16) f16 sB[128 * 64];
  const f16* Hb = H + (size_t)b * CCH * NTOK;
  int k0 = split * (NTOK / SPLITS);     // 1024 per split
  f32x4 acc[4][4] = {};
  int ldsrow = wid * 8 + (lane >> 3);   // 128B rows: 8 lanes/row
  int slot = lane & 7;                  // 16B slot within row
  int lr = lane & 15, lk = lane >> 4;

  const int NS = (NTOK / SPLITS) / 64;  // 16 K-steps of BK=64
  for (int ks = 0; ks < NS; ++ks) {
    int kk0 = k0 + ks * 64;
    __syncthreads();
#pragma unroll
    for (int i = 0; i < 4; ++i) {
      int row = ldsrow + i * 32;
      int cA = ((slot ^ (row & 7)) * 8);  // pre-swizzled global source column
      g2l16(Hb + (size_t)(m0 + row) * NTOK + kk0 + cA, &sA[i * 2048 + wid * 512]);
      g2l16(Hb + (size_t)(n0 + row) * NTOK + kk0 + cA, &sB[i * 2048 + wid * 512]);
    }
    asm volatile("s_waitcnt vmcnt(0)" ::: "memory");
    __syncthreads();
#pragma unroll
    for (int kk = 0; kk < 2; ++kk) {
      f16x8 af[4], bf[4];
#pragma unroll
      for (int mi = 0; mi < 4; ++mi) {
        int row = wr * 64 + mi * 16 + lr;
        int ks8 = (kk * 4 + lk) ^ (row & 7);
        af[mi] = *(const f16x8*)&sA[row * 64 + ks8 * 8];
      }
#pragma unroll
      for (int ni = 0; ni < 4; ++ni) {
        int row = wc * 64 + ni * 16 + lr;
        int ks8 = (kk * 4 + lk) ^ (row & 7);
        bf[ni] = *(const f16x8*)&sB[row * 64 + ks8 * 8];
      }
#pragma unroll
      for (int mi = 0; mi < 4; ++mi)
#pragma unroll
        for (int ni = 0; ni < 4; ++ni)
          acc[mi][ni] = __builtin_amdgcn_mfma_f32_16x16x32_f16(af[mi], bf[ni], acc[mi][ni], 0, 0, 0);
    }
  }

  float* Gb = G + (size_t)b * CCH * CCH;
#pragma unroll
  for (int mi = 0; mi < 4; ++mi)
#pragma unroll
    for (int j = 0; j < 4; ++j) {
      int rr2 = m0 + wr * 64 + mi * 16 + lk * 4 + j;
#pragma unroll
      for (int ni = 0; ni < 4; ++ni) {
        int cc = n0 + wc * 64 + ni * 16 + lr;
        atomicAdd(&Gb[(size_t)rr2 * CCH + cc], acc[mi][ni][j]);   // coalesced rows only
      }
    }
}

// ---------------- K3b: mirror upper off-diag tiles + cast full G -> G16 ------------
// G16 = fp16(G - 16384*I): diag shift keeps fp16 ulp small (diag~16384 -> ulp 16);
// the exact 16384*Wq rank-shift is restored in k_hgemm512's fp32 epilogue.
__global__ __launch_bounds__(256) void k_symm(float* __restrict__ G,
                                              f16* __restrict__ G16) {
  const int TI6[6] = {0, 0, 0, 1, 1, 2};
  const int TJ6[6] = {1, 2, 3, 2, 3, 3};
  int bx = blockIdx.x;               // [0,24): off-diag mirror+cast; [24,40): diag cast
  int b = blockIdx.y;
  float* Gb = G + (size_t)b * CCH * CCH;
  f16* Gh = G16 + (size_t)b * CCH * CCH;
  __shared__ float s[64][65];
  int t = threadIdx.x;
  int r = t >> 2, cg = (t & 3) * 16;
  int ib, jb;
  bool mirror = bx < 24;
  if (mirror) {
    int t6 = bx >> 2, sub = bx & 3;
    ib = TI6[t6] * 2 + (sub >> 1); jb = TJ6[t6] * 2 + (sub & 1);
  } else {
    int idx = bx - 24; int dt = idx >> 2, sub = idx & 3;
    ib = dt * 2 + (sub >> 1); jb = dt * 2 + (sub & 1);
  }
  int grow = ib * 64 + r, gcol0 = jb * 64 + cg;
  const float* src = &Gb[(size_t)grow * CCH + gcol0];
  f16 hv[16] __attribute__((aligned(16)));
#pragma unroll
  for (int k = 0; k < 4; ++k) {
    float4 v = *(const float4*)(src + k * 4);
    if (mirror) {
      s[r][cg + k * 4 + 0] = v.x; s[r][cg + k * 4 + 1] = v.y;
      s[r][cg + k * 4 + 2] = v.z; s[r][cg + k * 4 + 3] = v.w;
    }
    hv[k * 4 + 0] = (f16)(v.x - ((grow == gcol0 + k * 4 + 0) ? 16384.f : 0.f));
    hv[k * 4 + 1] = (f16)(v.y - ((grow == gcol0 + k * 4 + 1) ? 16384.f : 0.f));
    hv[k * 4 + 2] = (f16)(v.z - ((grow == gcol0 + k * 4 + 2) ? 16384.f : 0.f));
    hv[k * 4 + 3] = (f16)(v.w - ((grow == gcol0 + k * 4 + 3) ? 16384.f : 0.f));
  }
  f16* d16 = &Gh[(size_t)grow * CCH + gcol0];
  *(uint4*)&d16[0] = ((const uint4*)hv)[0];
  *(uint4*)&d16[8] = ((const uint4*)hv)[1];
  if (mirror) {
    __syncthreads();
    float* dst = &Gb[(size_t)(jb * 64 + r) * CCH + ib * 64 + cg];
    f16 hw[16] __attribute__((aligned(16)));
#pragma unroll
    for (int k = 0; k < 4; ++k) {
      float4 v;
      v.x = s[cg + k * 4 + 0][r]; v.y = s[cg + k * 4 + 1][r];
      v.z = s[cg + k * 4 + 2][r]; v.w = s[cg + k * 4 + 3][r];
      *(float4*)(dst + k * 4) = v;
      hw[k * 4 + 0] = (f16)v.x; hw[k * 4 + 1] = (f16)v.y;
      hw[k * 4 + 2] = (f16)v.z; hw[k * 4 + 3] = (f16)v.w;   // off-diag: no shift
    }
    f16* m16 = &Gh[(size_t)(jb * 64 + r) * CCH + ib * 64 + cg];
    *(uint4*)&m16[0] = ((const uint4*)hw)[0];
    *(uint4*)&m16[8] = ((const uint4*)hw)[1];
  }
}

// ---------------- K4: fp16 MFMA 512^3 GEMM: C[b] = A16 @ Bt16[b]^T ----------------
// A16 [512][512] shared across b; Bt16 is B TRANSPOSED ([n][k], k contiguous).
// CORR (T1 path): C += 16384 * corr[m][n] (fp32) -- restores G's diag shift.
template <bool HALF_OUT, bool CORR>
__global__ __launch_bounds__(256, 2) void k_hgemm512(const f16* __restrict__ A16,
                                                     const f16* __restrict__ Bt16,
                                                     void* __restrict__ Cv,
                                                     const float* __restrict__ corr) {
  int n0 = blockIdx.x * 128, m0 = blockIdx.y * 128, b = blockIdx.z;
  int t = threadIdx.x, lane = t & 63, wid = t >> 6;
  int wr = wid >> 1, wc = wid & 1;
  __shared__ __align__(16) f16 sA[128 * 64];
  __shared__ __align__(16) f16 sB[128 * 64];
  const f16* A = A16;
  const f16* Bp = Bt16 + (size_t)b * CCH * CCH;
  f32x4 acc[4][4] = {};
  int ldsrow = wid * 8 + (lane >> 3);
  int slot = lane & 7;
  int lr = lane & 15, lk = lane >> 4;
  for (int ks = 0; ks < 8; ++ks) {
    int kk0 = ks * 64;
    __syncthreads();
#pragma unroll
    for (int i = 0; i < 4; ++i) {
      int row = ldsrow + i * 32;
      int cA = ((slot ^ (row & 7)) * 8);
      g2l16(A + (size_t)(m0 + row) * CCH + kk0 + cA, &sA[i * 2048 + wid * 512]);
      g2l16(Bp + (size_t)(n0 + row) * CCH + kk0 + cA, &sB[i * 2048 + wid * 512]);
    }
    asm volatile("s_waitcnt vmcnt(0)" ::: "memory");
    __syncthreads();
#pragma unroll
    for (int kk = 0; kk < 2; ++kk) {
      f16x8 af[4], bf[4];
#pragma unroll
      for (int mi = 0; mi < 4; ++mi) {
        int row = wr * 64 + mi * 16 + lr;
        int ks8 = (kk * 4 + lk) ^ (row & 7);
        af[mi] = *(const f16x8*)&sA[row * 64 + ks8 * 8];
      }
#pragma unroll
      for (int ni = 0; ni < 4; ++ni) {
        int row = wc * 64 + ni * 16 + lr;
        int ks8 = (kk * 4 + lk) ^ (row & 7);
        bf[ni] = *(const f16x8*)&sB[row * 64 + ks8 * 8];
      }
#pragma unroll
      for (int mi = 0; mi < 4; ++mi)
#pragma unroll
        for (int ni = 0; ni < 4; ++ni)
          acc[mi][ni] = __builtin_amdgcn_mfma_f32_16x16x32_f16(af[mi], bf[ni], acc[mi][ni], 0, 0, 0);
    }
  }
#pragma unroll
  for (int mi = 0; mi < 4; ++mi)
#pragma unroll
    for (int j = 0; j < 4; ++j) {
      int o = m0 + wr * 64 + mi * 16 + lk * 4 + j;
#pragma unroll
      for (int ni = 0; ni < 4; ++ni) {
        int n = n0 + wc * 64 + ni * 16 + lr;
        float v = acc[mi][ni][j];
        if constexpr (CORR) v += 16384.f * corr[(size_t)o * CCH + n];
        if constexpr (HALF_OUT)
          ((f16*)Cv)[(size_t)b * CCH * CCH + (size_t)o * CCH + n] = (f16)v;
        else
          ((float*)Cv)[(size_t)b * CCH * CCH + (size_t)o * CCH + n] = v;
      }
    }
}

// ---------------- K4b-1: uvec[b][0:512]=Wq@s, [512:1024]=Wk@s (4 lanes/output) ----
__global__ __launch_bounds__(256) void k_uvec(const float* __restrict__ qkvw,
                                              const float* __restrict__ svec,
                                              float* __restrict__ uvec) {
  int o = blockIdx.x * 64 + (threadIdx.x >> 2);   // grid.x = 16
  int l = threadIdx.x & 3;
  int b = blockIdx.y;
  __shared__ float ss[512];
  for (int i = threadIdx.x; i < 512; i += 256) ss[i] = svec[b * CCH + i];
  __syncthreads();
  const float* wr_ = qkvw + (size_t)o * CCH + l * 128;
  const float* sp = ss + l * 128;
  float a = 0.f;
#pragma unroll
  for (int i = 0; i < 32; ++i) {
    float4 w = *(const float4*)&wr_[i * 4];
    a += w.x * sp[i * 4] + w.y * sp[i * 4 + 1] + w.z * sp[i * 4 + 2] + w.w * sp[i * 4 + 3];
  }
  a += __shfl_down(a, 2);
  a += __shfl_down(a, 1);
  if (l == 0) uvec[b * 1024 + o] = a;
}

// ---------------- K4b-2: L[b,h] += T1_h[64xK-chunk] @ Wk_h^T (split-K, atomics) ----
__global__ __launch_bounds__(256) void k_logits(const float* __restrict__ T1,
                                                const float* __restrict__ qkvw,
                                                float* __restrict__ L) {
  int kc = blockIdx.x;     // 8 chunks of 64 k
  int h = blockIdx.y, b = blockIdx.z;
  int t = threadIdx.x;
  int h64 = h * 64, k0 = kc * 64;
  __shared__ float sT[64][68];   // [d][k]
  __shared__ float sW[64][68];   // [k][e]
#pragma unroll
  for (int i = 0; i < 16; ++i) {
    int idx = i * 256 + t;
    int r = idx >> 6, c = idx & 63;
    sT[r][c] = T1[((size_t)b * CCH + h64 + r) * CCH + k0 + c];
    sW[c][r] = qkvw[(size_t)(512 + h64 + r) * CCH + k0 + c];
  }
  __syncthreads();
  int d = t >> 2, eg = (t & 3) * 16;
  float acc[16] = {};
  for (int k = 0; k < 64; ++k) {
    float a = sT[d][k];
    float4 w0 = *(const float4*)&sW[k][eg];
    float4 w1 = *(const float4*)&sW[k][eg + 4];
    float4 w2 = *(const float4*)&sW[k][eg + 8];
    float4 w3 = *(const float4*)&sW[k][eg + 12];
    acc[0] += a * w0.x;  acc[1] += a * w0.y;  acc[2] += a * w0.z;  acc[3] += a * w0.w;
    acc[4] += a * w1.x;  acc[5] += a * w1.y;  acc[6] += a * w1.z;  acc[7] += a * w1.w;
    acc[8] += a * w2.x;  acc[9] += a * w2.y;  acc[10] += a * w2.z; acc[11] += a * w2.w;
    acc[12] += a * w3.x; acc[13] += a * w3.y; acc[14] += a * w3.z; acc[15] += a * w3.w;
  }
  float* Lrow = &L[(((size_t)b * NHEAD + h) * 64 + d) * 64 + eg];
#pragma unroll
  for (int i = 0; i < 16; ++i) atomicAdd(&Lrow[i], acc[i]);
}

// ---------------- K4b-3: softmax rows + rank-1 bias terms -> P, pbv ----------------
__global__ __launch_bounds__(64) void k_softmax(const float* __restrict__ L,
                                                const float* __restrict__ uvec,
                                                const float* __restrict__ qkvb,
                                                float* __restrict__ P,
                                                float* __restrict__ pbv) {
  int bh = blockIdx.x;           // b*8 + h
  int b = bh >> 3, h = bh & 7;
  int d = threadIdx.x;           // 0..63
  int h64 = h * 64;
  __shared__ float sbk[64], sbv[64], suk[64];
  sbk[d] = qkvb[512 + h64 + d];
  sbv[d] = qkvb[1024 + h64 + d];
  suk[d] = uvec[b * 1024 + 512 + h64 + d];
  __syncthreads();
  float uq = uvec[b * 1024 + h64 + d];
  float bq = qkvb[h64 + d];
  float l[64];
  const float* Lr = &L[((size_t)bh * 64 + d) * 64];
  float m = -1e30f;
#pragma unroll
  for (int e = 0; e < 64; ++e) {
    float v = (Lr[e] + uq * sbk[e] + bq * suk[e] + 16384.f * bq * sbk[e]) * 0.125f;
    l[e] = v;
    m = fmaxf(m, v);
  }
  float sum = 0.f;
#pragma unroll
  for (int e = 0; e < 64; ++e) { float p = expf(l[e] - m); l[e] = p; sum += p; }
  float r = 1.f / sum, pb = 0.f;
  float* Pr = &P[((size_t)bh * 64 + d) * 64];
#pragma unroll
  for (int e = 0; e < 64; ++e) { float p = l[e] * r; Pr[e] = p; pb += p * sbv[e]; }
  pbv[b * CCH + h64 + d] = pb;
}

// ---------------- K4b-4: Rt16[b, c, h64+d] = sum_e P[b,h,d,e] Wv[h64+e][c] --------
// Transposed fp16 output so the M-GEMM's B-operand is [n][k]-contiguous.
__global__ __launch_bounds__(256) void k_pv(const float* __restrict__ P,
                                            const float* __restrict__ qkvw,
                                            f16* __restrict__ Rt16) {
  int ct = blockIdx.x;     // 8 c-tiles of 64
  int h = blockIdx.y, b = blockIdx.z;
  int t = threadIdx.x;
  int h64 = h * 64, c0 = ct * 64;
  __shared__ float sPt[64][68];  // [e][d] (P transposed)
  __shared__ float sW[64][68];   // [e][c]
#pragma unroll
  for (int i = 0; i < 16; ++i) {
    int idx = i * 256 + t;
    int rr = idx >> 6, c = idx & 63;
    sPt[c][rr] = P[(((size_t)b * NHEAD + h) * 64 + rr) * 64 + c];  // sPt[e][d]=P[d][e]
    sW[rr][c] = qkvw[(size_t)(1024 + h64 + rr) * CCH + c0 + c];
  }
  __syncthreads();
  int cl = t >> 2, dg = (t & 3) * 16;
  float acc[16] = {};
  for (int e = 0; e < 64; ++e) {
    float w = sW[e][cl];
    float4 p0 = *(const float4*)&sPt[e][dg];
    float4 p1 = *(const float4*)&sPt[e][dg + 4];
    float4 p2 = *(const float4*)&sPt[e][dg + 8];
    float4 p3 = *(const float4*)&sPt[e][dg + 12];
    acc[0]  += w * p0.x; acc[1]  += w * p0.y; acc[2]  += w * p0.z; acc[3]  += w * p0.w;
    acc[4]  += w * p1.x; acc[5]  += w * p1.y; acc[6]  += w * p1.z; acc[7]  += w * p1.w;
    acc[8]  += w * p2.x; acc[9]  += w * p2.y; acc[10] += w * p2.z; acc[11] += w * p2.w;
    acc[12] += w * p3.x; acc[13] += w * p3.y; acc[14] += w * p3.z; acc[15] += w * p3.w;
  }
  f16 hv[16] __attribute__((aligned(16)));
#pragma unroll
  for (int i = 0; i < 16; ++i) hv[i] = (f16)acc[i];
  f16* dst = &Rt16[((size_t)b * CCH + c0 + cl) * CCH + h64 + dg];
  *(uint4*)&dst[0] = ((const uint4*)hv)[0];
  *(uint4*)&dst[8] = ((const uint4*)hv)[1];
}

// ---------------- K4d: cvec = out_w @ pbv + out_b (4 lanes/output) ----------------
__global__ __launch_bounds__(256) void k_cvec(const float* __restrict__ outw,
                                              const float* __restrict__ outb,
                                              const float* __restrict__ pbv,
                                              float* __restrict__ cvec) {
  int o = blockIdx.x * 64 + (threadIdx.x >> 2);   // grid.x = 8
  int l = threadIdx.x & 3;
  int b = blockIdx.y;
  __shared__ float sp[512];
  for (int i = threadIdx.x; i < 512; i += 256) sp[i] = pbv[b * CCH + i];
  __syncthreads();
  const float* wr_ = outw + (size_t)o * CCH + l * 128;
  const float* spp = sp + l * 128;
  float a = 0.f;
#pragma unroll
  for (int i = 0; i < 32; ++i) {
    float4 w = *(const float4*)&wr_[i * 4];
    a += w.x * spp[i * 4] + w.y * spp[i * 4 + 1] + w.z * spp[i * 4 + 2] + w.w * spp[i * 4 + 3];
  }
  a += __shfl_down(a, 2);
  a += __shfl_down(a, 1);
  if (l == 0) cvec[b * CCH + o] = a + outb[o];
}

// ---------------- K5: out = x + M16 @ H + cvec (fp16 MFMA, transposed fragment) ----
// R14: mfma(bf, af) puts 4 CONSECUTIVE-n outputs in each lane's regs ->
// float4 x-load / float4 store epilogue (4x fewer epilogue memory instrs).
__global__ __launch_bounds__(256, 2) void k_out(const f16* __restrict__ M16,
                                                const f16* __restrict__ Ht,
                                                const float* __restrict__ x,
                                                const float* __restrict__ cvec,
                                                float* __restrict__ out) {
  int nt = blockIdx.x;   // 128 n-tiles
  int mt = blockIdx.y;   // 4 o-tiles
  int b = blockIdx.z;
  int m0 = mt * 128, n0 = nt * 128;
  int t = threadIdx.x, lane = t & 63, wid = t >> 6;
  int wr = wid >> 1, wc = wid & 1;
  __shared__ __align__(16) f16 sA[128 * 64];
  __shared__ __align__(16) f16 sB[128 * 64];
  const f16* A = M16 + (size_t)b * CCH * CCH;
  const f16* Bp = Ht + (size_t)b * NTOK * CCH;
  f32x4 acc[4][4] = {};
  int ldsrow = wid * 8 + (lane >> 3);
  int slot = lane & 7;
  int lr = lane & 15, lk = lane >> 4;
  for (int ks = 0; ks < 8; ++ks) {
    int kk0 = ks * 64;
    __syncthreads();
#pragma unroll
    for (int i = 0; i < 4; ++i) {
      int row = ldsrow + i * 32;
      int cA = ((slot ^ (row & 7)) * 8);
      g2l16(A + (size_t)(m0 + row) * CCH + kk0 + cA, &sA[i * 2048 + wid * 512]);
      g2l16(Bp + (size_t)(n0 + row) * CCH + kk0 + cA, &sB[i * 2048 + wid * 512]);
    }
    asm volatile("s_waitcnt vmcnt(0)" ::: "memory");
    __syncthreads();
#pragma unroll
    for (int kk = 0; kk < 2; ++kk) {
      f16x8 af[4], bf[4];
#pragma unroll
      for (int mi = 0; mi < 4; ++mi) {
        int row = wr * 64 + mi * 16 + lr;
        int ks8 = (kk * 4 + lk) ^ (row & 7);
        af[mi] = *(const f16x8*)&sA[row * 64 + ks8 * 8];
      }
#pragma unroll
      for (int ni = 0; ni < 4; ++ni) {
        int row = wc * 64 + ni * 16 + lr;
        int ks8 = (kk * 4 + lk) ^ (row & 7);
        bf[ni] = *(const f16x8*)&sB[row * 64 + ks8 * 8];
      }
#pragma unroll
      for (int mi = 0; mi < 4; ++mi)
#pragma unroll
        for (int ni = 0; ni < 4; ++ni)   // swapped: D[n][o] fragment
          acc[mi][ni] = __builtin_amdgcn_mfma_f32_16x16x32_f16(bf[ni], af[mi], acc[mi][ni], 0, 0, 0);
    }
  }

  // Epilogue: lane holds o = ..+lr (col), n-quad = ..+lk*4 (row,4 regs consecutive n)
  const float* xb = x + ((size_t)b * CCH) * NTOK;
  float* ob = out + ((size_t)b * CCH) * NTOK;
#pragma unroll
  for (int mi = 0; mi < 4; ++mi) {
    int o = m0 + wr * 64 + mi * 16 + lr;
    float cv = cvec[b * CCH + o];
    size_t rowoff = (size_t)o * NTOK;
#pragma unroll
    for (int ni = 0; ni < 4; ++ni) {
      int n = n0 + wc * 64 + ni * 16 + lk * 4;
      float4 xv = *(const float4*)&xb[rowoff + n];
      float4 ov;
      ov.x = xv.x + acc[mi][ni][0] + cv;
      ov.y = xv.y + acc[mi][ni][1] + cv;
      ov.z = xv.z + acc[mi][ni][2] + cv;
      ov.w = xv.w + acc[mi][ni][3] + cv;
      *(float4*)&ob[rowoff + n] = ov;
    }
  }
}

extern "C" void kernel_launch(void* const* d_in, const int* in_sizes, int n_in,
                              void* d_out, int out_size, void* d_ws, size_t ws_size,
                              hipStream_t stream) {
  const float* x    = (const float*)d_in[0];
  const float* gw   = (const float*)d_in[1];
  const float* gb   = (const float*)d_in[2];
  const float* qkvw = (const float*)d_in[3];
  const float* qkvb = (const float*)d_in[4];
  const float* outw = (const float*)d_in[5];
  const float* outb = (const float*)d_in[6];
  int B = in_sizes[0] / (CCH * NTOK);   // 4

  char* ws = (char*)d_ws;
  size_t off = 0;
  f16* H    = (f16*)(ws + off);   off += (size_t)B * CCH * NTOK * 2;   // 64 MiB
  f16* Ht   = (f16*)(ws + off);   off += (size_t)B * NTOK * CCH * 2;   // 64 MiB
  float* G  = (float*)(ws + off); off += (size_t)B * CCH * CCH * 4;    // 4 MiB
  float* T1 = (float*)(ws + off); off += (size_t)B * CCH * CCH * 4;    // 4 MiB
  f16* G16  = (f16*)(ws + off);   off += (size_t)B * CCH * CCH * 2;    // 2 MiB
  f16* Rt16 = (f16*)(ws + off);   off += (size_t)B * CCH * CCH * 2;    // 2 MiB
  f16* M16  = (f16*)(ws + off);   off += (size_t)B * CCH * CCH * 2;    // 2 MiB
  f16* Wq16 = (f16*)(ws + off);   off += (size_t)CCH * CCH * 2;        // 0.5 MiB
  f16* Ow16 = (f16*)(ws + off);   off += (size_t)CCH * CCH * 2;        // 0.5 MiB
  float* P  = (float*)(ws + off); off += (size_t)B * NHEAD * 64 * 64 * 4;  // 512 KiB
  float* uvec  = (float*)(ws + off); off += (size_t)B * 1024 * 4;
  float* pbv   = (float*)(ws + off); off += (size_t)B * CCH * 4;
  float* cvec  = (float*)(ws + off); off += (size_t)B * CCH * 4;
  // zero-init region: stats, svec, L (contiguous -> single memset)
  float* stats = (float*)(ws + off); off += (size_t)B * 8 * 2 * 4;
  float* svec  = (float*)(ws + off); off += (size_t)B * CCH * 4;
  float* L     = (float*)(ws + off); off += (size_t)B * NHEAD * 64 * 64 * 4;  // 512 KiB
  size_t zbytes = (size_t)(B * 8 * 2 + B * CCH + B * NHEAD * 64 * 64) * 4;

  hipMemsetAsync(G, 0, (size_t)B * CCH * CCH * 4, stream);
  hipMemsetAsync(stats, 0, zbytes, stream);

  k_cast2<<<dim3(CCH * CCH / 1024, 2), 256, 0, stream>>>(qkvw, Wq16, outw, Ow16,
                                                         CCH * CCH / 4);
  k_stats<<<dim3(32, B * 8), 256, 0, stream>>>(x, stats);
  k_gnorm<<<dim3(64, 8, B), 256, 0, stream>>>(x, gw, gb, stats, H, Ht, svec);
  k_syrk<<<dim3(10, SPLITS, B), 256, 0, stream>>>(H, G);
  k_symm<<<dim3(40, B), 256, 0, stream>>>(G, G16);
  // T1 = Wq @ G  (B-operand = G16 via symmetry; +16384*Wq fp32 correction)
  k_hgemm512<false, true><<<dim3(4, 4, B), 256, 0, stream>>>(Wq16, G16, T1, qkvw);
  k_uvec<<<dim3(16, B), 256, 0, stream>>>(qkvw, svec, uvec);
  k_logits<<<dim3(8, NHEAD, B), 256, 0, stream>>>(T1, qkvw, L);
  k_softmax<<<dim3(B * NHEAD), 64, 0, stream>>>(L, uvec, qkvb, P, pbv);
  k_pv<<<dim3(8, NHEAD, B), 256, 0, stream>>>(P, qkvw, Rt16);
  // M16 = out_w @ R  (B-operand = Rt16, already transposed)
  k_hgemm512<true, false><<<dim3(4, 4, B), 256, 0, stream>>>(Ow16, Rt16, M16, nullptr);
  k_cvec<<<dim3(8, B), 256, 0, stream>>>(outw, outb, pbv, cvec);
  k_out<<<dim3(128, 4, B), 256, 0, stream>>>(M16, Ht, x, cvec, (float*)d_out);
}

// Round 15
// 302.267 us; speedup vs baseline: 1.3621x; 1.1871x over previous
//
#include <hip/hip_runtime.h>
#include <hip/hip_fp16.h>

// AttentionBlock3D: channel attention. B=4, C=512, N=T*H*W=16384, 8 heads, d=64.
// Algebraic reduction: result = x + M*H + c, with
//   G = H H^T (per batch, SYMMETRIC -> upper tiles only + k_symm mirror+cast),
//   logits = scale*(Wq G Wk^T + rank-1), P = softmax per head,
//   M = out_w * blockdiag(P) * Wv, c = out_w * blockdiag(P) * bv + out_b.
//
// MFMA kernel geometry: LOCKED at measured-best (R9):
//   BK=64 (128B rows, 8x16B slots, XOR-swizzle slot^(row&7) => 0 bank conflicts),
//   single LDS buffer (32 KiB), 2 barriers per K-step, __launch_bounds__(256,2).
//   k_out plateau 84-85us across 7 variants (R9-R14) -> closed.
// R13: fp32 512^3 GEMMs -> fp16 MFMA (+16384*I diag-shift trick). 393 -> 360us.
// R15: fused k_attn (logits MFMA + softmax + PV MFMA + uvec + pbv per (b,h));
//   T1 now fp16 (T1h); removes k_uvec/k_logits/k_softmax/k_pv + L memset.

#define CCH 512
#define NTOK 16384
#define NHEAD 8

typedef _Float16 f16;
typedef _Float16 f16x8 __attribute__((ext_vector_type(8)));
typedef float f32x4 __attribute__((ext_vector_type(4)));

__device__ __forceinline__ void g2l16(const void* g, void* l) {
  __builtin_amdgcn_global_load_lds((const __attribute__((address_space(1))) void*)g,
                                   (__attribute__((address_space(3))) void*)l,
                                   16, 0, 0);
}

// ---------------- K0a: fp32 -> fp16 cast (full qkvw; outw) ----------------
__global__ __launch_bounds__(256) void k_cast2(const float* __restrict__ srcA,
                                               f16* __restrict__ dstA,
                                               const float* __restrict__ srcB,
                                               f16* __restrict__ dstB) {
  int i = blockIdx.x * 256 + threadIdx.x;
  int n4 = blockIdx.y ? (CCH * CCH / 4) : (3 * CCH * CCH / 4);
  const float* src = blockIdx.y ? srcB : srcA;
  f16* dst = blockIdx.y ? dstB : dstA;
  if (i < n4) {
    float4 v = *(const float4*)&src[i * 4];
    f16 h[4] __attribute__((aligned(8)));
    h[0] = (f16)v.x; h[1] = (f16)v.y; h[2] = (f16)v.z; h[3] = (f16)v.w;
    *(uint2*)&dst[i * 4] = *(const uint2*)h;
  }
}

// ---------------- K0b: Wvt16[c][e] = fp16(qkvw[1024+e][c]) (transpose-cast) -------
__global__ __launch_bounds__(256) void k_wvt(const float* __restrict__ qkvw,
                                             f16* __restrict__ Wvt16) {
  int et = blockIdx.x, ct = blockIdx.y;   // 8 x 8 tiles of 64x64
  __shared__ f16 tl[64][72];
  int t = threadIdx.x;
  int r = t >> 2, cq = (t & 3) * 16;
  const float* src = &qkvw[(size_t)(1024 + et * 64 + r) * CCH + ct * 64 + cq];
#pragma unroll
  for (int k = 0; k < 4; ++k) {
    float4 v = *(const float4*)(src + k * 4);
    tl[r][cq + k * 4 + 0] = (f16)v.x; tl[r][cq + k * 4 + 1] = (f16)v.y;
    tl[r][cq + k * 4 + 2] = (f16)v.z; tl[r][cq + k * 4 + 3] = (f16)v.w;
  }
  __syncthreads();
  f16 hv[16] __attribute__((aligned(16)));
#pragma unroll
  for (int j = 0; j < 16; ++j) hv[j] = tl[cq + j][r];
  f16* dst = &Wvt16[(size_t)(ct * 64 + r) * CCH + et * 64 + cq];
  *(uint4*)&dst[0] = ((const uint4*)hv)[0];
  *(uint4*)&dst[8] = ((const uint4*)hv)[1];
}

// ---------------- K1: GroupNorm stats (sum, sumsq) per (b, group) ----------------
__global__ __launch_bounds__(256) void k_stats(const float* __restrict__ x,
                                               float* __restrict__ stats) {
  int bg = blockIdx.y;
  int chunk = blockIdx.x;       // 0..31
  const float4* p = (const float4*)(x + (size_t)bg * (64ull * NTOK)) + (size_t)chunk * 8192;
  float s = 0.f, q = 0.f;
  for (int i = threadIdx.x; i < 8192; i += 256) {
    float4 v = p[i];
    s += v.x + v.y + v.z + v.w;
    q += v.x * v.x + v.y * v.y + v.z * v.z + v.w * v.w;
  }
  for (int off = 32; off; off >>= 1) { s += __shfl_down(s, off); q += __shfl_down(q, off); }
  __shared__ float ls[4], lq[4];
  int wid = threadIdx.x >> 6, lane = threadIdx.x & 63;
  if (lane == 0) { ls[wid] = s; lq[wid] = q; }
  __syncthreads();
  if (threadIdx.x == 0) {
    atomicAdd(&stats[bg * 2 + 0], ls[0] + ls[1] + ls[2] + ls[3]);
    atomicAdd(&stats[bg * 2 + 1], lq[0] + lq[1] + lq[2] + lq[3]);
  }
}

// ---------------- K2: normalize -> H (fp16, [b][c][n]) and Ht (fp16, [b][n][c]), s = H*1 ----
__global__ __launch_bounds__(256) void k_gnorm(const float* __restrict__ x,
                                               const float* __restrict__ gw,
                                               const float* __restrict__ gb,
                                               const float* __restrict__ stats,
                                               f16* __restrict__ H, f16* __restrict__ Ht,
                                               float* __restrict__ svec) {
  int nc = blockIdx.x;   // n chunk (256 tokens)
  int cg = blockIdx.y;   // channel group (64 ch) == GN group
  int b = blockIdx.z;
  int t = threadIdx.x;
  __shared__ f16 T2[64][260];
  __shared__ float svp[4][64];
  float sum = stats[(b * 8 + cg) * 2], sq = stats[(b * 8 + cg) * 2 + 1];
  const float inv = 1.f / (64.f * (float)NTOK);
  float mean = sum * inv;
  float var = fmaxf(sq * inv - mean * mean, 0.f);
  float rsig = rsqrtf(var + 1e-5f);
  int c0 = cg * 64, n0 = nc * 256;
  int tq = t & 63, rr0 = t >> 6;
#pragma unroll
  for (int it = 0; it < 16; ++it) {
    int r = it * 4 + rr0;
    int c = c0 + r;
    float a = gw[c] * rsig;
    float bb = gb[c] - mean * a;
    size_t idx = ((size_t)(b * CCH + c)) * NTOK + n0 + tq * 4;
    float4 xv = *(const float4*)&x[idx];
    f16 hh[4] __attribute__((aligned(8)));
    hh[0] = (f16)(xv.x * a + bb);
    hh[1] = (f16)(xv.y * a + bb);
    hh[2] = (f16)(xv.z * a + bb);
    hh[3] = (f16)(xv.w * a + bb);
    *(uint2*)&H[idx] = *(const uint2*)hh;
    *(uint2*)&T2[r][tq * 4] = *(const uint2*)hh;
  }
  __syncthreads();
  {
    int c = t & 63, q = t >> 6;
    float acc = 0.f;
#pragma unroll
    for (int j = 0; j < 64; ++j) acc += (float)T2[c][q * 64 + j];
    svp[q][c] = acc;
  }
  __syncthreads();
  if (t < 64) {
    atomicAdd(&svec[b * CCH + c0 + t],
              svp[0][t] + svp[1][t] + svp[2][t] + svp[3][t]);
  }
  int s8 = t & 7, nl = t >> 3;
#pragma unroll
  for (int it = 0; it < 8; ++it) {
    int n = it * 32 + nl;
    f16 g[8] __attribute__((aligned(16)));
#pragma unroll
    for (int j = 0; j < 8; ++j) g[j] = T2[s8 * 8 + j][n];
    *(uint4*)&Ht[((size_t)b * NTOK + n0 + n) * CCH + c0 + s8 * 8] = *(const uint4*)g;
  }
}

// ---------------- K3: G = H H^T, upper tiles, split-K=16, BK=64 single-buf (32KB) ----
#define SPLITS 16
__global__ __launch_bounds__(256, 2) void k_syrk(const f16* __restrict__ H,
                                                 float* __restrict__ G) {
  const int TI[10] = {0, 0, 0, 0, 1, 1, 1, 2, 2, 3};
  const int TJ[10] = {0, 1, 2, 3, 1, 2, 3, 2, 3, 3};
  int tile = blockIdx.x;
  int split = blockIdx.y;
  int b = blockIdx.z;
  int ii = TI[tile], jj = TJ[tile];
  int m0 = ii * 128, n0 = jj * 128;
  int t = threadIdx.x, lane = t & 63, wid = t >> 6;
  int wr = wid >> 1, wc = wid & 1;
  __shared__ __align__(16) f16 sA[128 * 64];
  __shared__ __align__(16) f16 sB[128 * 64];
  const f16* Hb = H + (size_t)b * CCH * NTOK;
  int k0 = split * (NTOK / SPLITS);
  f32x4 acc[4][4] = {};
  int ldsrow = wid * 8 + (lane >> 3);
  int slot = lane & 7;
  int lr = lane & 15, lk = lane >> 4;

  const int NS = (NTOK / SPLITS) / 64;
  for (int ks = 0; ks < NS; ++ks) {
    int kk0 = k0 + ks * 64;
    __syncthreads();
#pragma unroll
    for (int i = 0; i < 4; ++i) {
      int row = ldsrow + i * 32;
      int cA = ((slot ^ (row & 7)) * 8);
      g2l16(Hb + (size_t)(m0 + row) * NTOK + kk0 + cA, &sA[i * 2048 + wid * 512]);
      g2l16(Hb + (size_t)(n0 + row) * NTOK + kk0 + cA, &sB[i * 2048 + wid * 512]);
    }
    asm volatile("s_waitcnt vmcnt(0)" ::: "memory");
    __syncthreads();
#pragma unroll
    for (int kk = 0; kk < 2; ++kk) {
      f16x8 af[4], bf[4];
#pragma unroll
      for (int mi = 0; mi < 4; ++mi) {
        int row = wr * 64 + mi * 16 + lr;
        int ks8 = (kk * 4 + lk) ^ (row & 7);
        af[mi] = *(const f16x8*)&sA[row * 64 + ks8 * 8];
      }
#pragma unroll
      for (int ni = 0; ni < 4; ++ni) {
        int row = wc * 64 + ni * 16 + lr;
        int ks8 = (kk * 4 + lk) ^ (row & 7);
        bf[ni] = *(const f16x8*)&sB[row * 64 + ks8 * 8];
      }
#pragma unroll
      for (int mi = 0; mi < 4; ++mi)
#pragma unroll
        for (int ni = 0; ni < 4; ++ni)
          acc[mi][ni] = __builtin_amdgcn_mfma_f32_16x16x32_f16(af[mi], bf[ni], acc[mi][ni], 0, 0, 0);
    }
  }

  float* Gb = G + (size_t)b * CCH * CCH;
#pragma unroll
  for (int mi = 0; mi < 4; ++mi)
#pragma unroll
    for (int j = 0; j < 4; ++j) {
      int rr2 = m0 + wr * 64 + mi * 16 + lk * 4 + j;
#pragma unroll
      for (int ni = 0; ni < 4; ++ni) {
        int cc = n0 + wc * 64 + ni * 16 + lr;
        atomicAdd(&Gb[(size_t)rr2 * CCH + cc], acc[mi][ni][j]);
      }
    }
}

// ---------------- K3b: mirror upper off-diag tiles + cast full G -> G16 ------------
__global__ __launch_bounds__(256) void k_symm(float* __restrict__ G,
                                              f16* __restrict__ G16) {
  const int TI6[6] = {0, 0, 0, 1, 1, 2};
  const int TJ6[6] = {1, 2, 3, 2, 3, 3};
  int bx = blockIdx.x;
  int b = blockIdx.y;
  float* Gb = G + (size_t)b * CCH * CCH;
  f16* Gh = G16 + (size_t)b * CCH * CCH;
  __shared__ float s[64][65];
  int t = threadIdx.x;
  int r = t >> 2, cg = (t & 3) * 16;
  int ib, jb;
  bool mirror = bx < 24;
  if (mirror) {
    int t6 = bx >> 2, sub = bx & 3;
    ib = TI6[t6] * 2 + (sub >> 1); jb = TJ6[t6] * 2 + (sub & 1);
  } else {
    int idx = bx - 24; int dt = idx >> 2, sub = idx & 3;
    ib = dt * 2 + (sub >> 1); jb = dt * 2 + (sub & 1);
  }
  int grow = ib * 64 + r, gcol0 = jb * 64 + cg;
  const float* src = &Gb[(size_t)grow * CCH + gcol0];
  f16 hv[16] __attribute__((aligned(16)));
#pragma unroll
  for (int k = 0; k < 4; ++k) {
    float4 v = *(const float4*)(src + k * 4);
    if (mirror) {
      s[r][cg + k * 4 + 0] = v.x; s[r][cg + k * 4 + 1] = v.y;
      s[r][cg + k * 4 + 2] = v.z; s[r][cg + k * 4 + 3] = v.w;
    }
    hv[k * 4 + 0] = (f16)(v.x - ((grow == gcol0 + k * 4 + 0) ? 16384.f : 0.f));
    hv[k * 4 + 1] = (f16)(v.y - ((grow == gcol0 + k * 4 + 1) ? 16384.f : 0.f));
    hv[k * 4 + 2] = (f16)(v.z - ((grow == gcol0 + k * 4 + 2) ? 16384.f : 0.f));
    hv[k * 4 + 3] = (f16)(v.w - ((grow == gcol0 + k * 4 + 3) ? 16384.f : 0.f));
  }
  f16* d16 = &Gh[(size_t)grow * CCH + gcol0];
  *(uint4*)&d16[0] = ((const uint4*)hv)[0];
  *(uint4*)&d16[8] = ((const uint4*)hv)[1];
  if (mirror) {
    __syncthreads();
    float* dst = &Gb[(size_t)(jb * 64 + r) * CCH + ib * 64 + cg];
    f16 hw[16] __attribute__((aligned(16)));
#pragma unroll
    for (int k = 0; k < 4; ++k) {
      float4 v;
      v.x = s[cg + k * 4 + 0][r]; v.y = s[cg + k * 4 + 1][r];
      v.z = s[cg + k * 4 + 2][r]; v.w = s[cg + k * 4 + 3][r];
      *(float4*)(dst + k * 4) = v;
      hw[k * 4 + 0] = (f16)v.x; hw[k * 4 + 1] = (f16)v.y;
      hw[k * 4 + 2] = (f16)v.z; hw[k * 4 + 3] = (f16)v.w;
    }
    f16* m16 = &Gh[(size_t)(jb * 64 + r) * CCH + ib * 64 + cg];
    *(uint4*)&m16[0] = ((const uint4*)hw)[0];
    *(uint4*)&m16[8] = ((const uint4*)hw)[1];
  }
}

// ---------------- K4: fp16 MFMA 512^3 GEMM: C[b] = A16 @ Bt16[b]^T ----------------
// CORR: C += 16384 * corr[m][n] (fp32) -- restores G's diag shift.
template <bool HALF_OUT, bool CORR>
__global__ __launch_bounds__(256, 2) void k_hgemm512(const f16* __restrict__ A16,
                                                     const f16* __restrict__ Bt16,
                                                     void* __restrict__ Cv,
                                                     const float* __restrict__ corr) {
  int n0 = blockIdx.x * 128, m0 = blockIdx.y * 128, b = blockIdx.z;
  int t = threadIdx.x, lane = t & 63, wid = t >> 6;
  int wr = wid >> 1, wc = wid & 1;
  __shared__ __align__(16) f16 sA[128 * 64];
  __shared__ __align__(16) f16 sB[128 * 64];
  const f16* A = A16;
  const f16* Bp = Bt16 + (size_t)b * CCH * CCH;
  f32x4 acc[4][4] = {};
  int ldsrow = wid * 8 + (lane >> 3);
  int slot = lane & 7;
  int lr = lane & 15, lk = lane >> 4;
  for (int ks = 0; ks < 8; ++ks) {
    int kk0 = ks * 64;
    __syncthreads();
#pragma unroll
    for (int i = 0; i < 4; ++i) {
      int row = ldsrow + i * 32;
      int cA = ((slot ^ (row & 7)) * 8);
      g2l16(A + (size_t)(m0 + row) * CCH + kk0 + cA, &sA[i * 2048 + wid * 512]);
      g2l16(Bp + (size_t)(n0 + row) * CCH + kk0 + cA, &sB[i * 2048 + wid * 512]);
    }
    asm volatile("s_waitcnt vmcnt(0)" ::: "memory");
    __syncthreads();
#pragma unroll
    for (int kk = 0; kk < 2; ++kk) {
      f16x8 af[4], bf[4];
#pragma unroll
      for (int mi = 0; mi < 4; ++mi) {
        int row = wr * 64 + mi * 16 + lr;
        int ks8 = (kk * 4 + lk) ^ (row & 7);
        af[mi] = *(const f16x8*)&sA[row * 64 + ks8 * 8];
      }
#pragma unroll
      for (int ni = 0; ni < 4; ++ni) {
        int row = wc * 64 + ni * 16 + lr;
        int ks8 = (kk * 4 + lk) ^ (row & 7);
        bf[ni] = *(const f16x8*)&sB[row * 64 + ks8 * 8];
      }
#pragma unroll
      for (int mi = 0; mi < 4; ++mi)
#pragma unroll
        for (int ni = 0; ni < 4; ++ni)
          acc[mi][ni] = __builtin_amdgcn_mfma_f32_16x16x32_f16(af[mi], bf[ni], acc[mi][ni], 0, 0, 0);
    }
  }
#pragma unroll
  for (int mi = 0; mi < 4; ++mi)
#pragma unroll
    for (int j = 0; j < 4; ++j) {
      int o = m0 + wr * 64 + mi * 16 + lk * 4 + j;
#pragma unroll
      for (int ni = 0; ni < 4; ++ni) {
        int n = n0 + wc * 64 + ni * 16 + lr;
        float v = acc[mi][ni][j];
        if constexpr (CORR) v += 16384.f * corr[(size_t)o * CCH + n];
        if constexpr (HALF_OUT)
          ((f16*)Cv)[(size_t)b * CCH * CCH + (size_t)o * CCH + n] = (f16)v;
        else
          ((float*)Cv)[(size_t)b * CCH * CCH + (size_t)o * CCH + n] = v;
      }
    }
}

// ---------------- K5: fused per-(b,h) attention ----------------
// logits L = T1h_h @ Wk_h^T (MFMA, K=512) + rank-1 bias terms, scaled;
// softmax rows -> P (fp16 in LDS) + pbv; R = P @ Wv_h via Wvt16 (MFMA, K=64),
// written TRANSPOSED as Rt16[b][c][h64+d]. uvec folded in (fp32 VALU).
__global__ __launch_bounds__(256) void k_attn(const f16* __restrict__ T1h,
                                              const f16* __restrict__ Wqkv16,
                                              const f16* __restrict__ Wvt16,
                                              const float* __restrict__ qkvw,
                                              const float* __restrict__ qkvb,
                                              const float* __restrict__ svec,
                                              f16* __restrict__ Rt16,
                                              float* __restrict__ pbv) {
  int h = blockIdx.x, b = blockIdx.y;
  int h64 = h * 64;
  int t = threadIdx.x, lane = t & 63, wid = t >> 6;
  int lr = lane & 15, lk = lane >> 4;
  __shared__ float ss[512];
  __shared__ float suq[64], suk[64], sbq[64], sbk[64], sbv[64];
  __shared__ float Lsm[64][68];
  __shared__ f16 Psm[64][72];

  for (int i = t; i < 512; i += 256) ss[i] = svec[b * CCH + i];
  if (t < 64) {
    sbq[t] = qkvb[h64 + t];
    sbk[t] = qkvb[512 + h64 + t];
    sbv[t] = qkvb[1024 + h64 + t];
  }
  __syncthreads();
  // uvec (fp32): uq[d] = Wq_h[d] . s ; uk[e] = Wk_h[e] . s
  if (t < 128) {
    int o = t & 63; bool isk = t >= 64;
    const float* wr_ = qkvw + (size_t)((isk ? 512 : 0) + h64 + o) * CCH;
    float a = 0.f;
#pragma unroll
    for (int i = 0; i < 128; ++i) {
      float4 w = *(const float4*)&wr_[i * 4];
      a += w.x * ss[i * 4] + w.y * ss[i * 4 + 1] + w.z * ss[i * 4 + 2] + w.w * ss[i * 4 + 3];
    }
    (isk ? suk : suq)[o] = a;
  }
  // logits MFMA: 4 waves as 2x2 over 64x64, K=512 (operands straight from global, L2-hot)
  int wr = wid >> 1, wc = wid & 1;
  f32x4 lacc[2][2] = {};
  const f16* Ab = T1h + (size_t)b * CCH * CCH;
  const f16* Bb = Wqkv16 + (size_t)(512 + h64) * CCH;
  for (int ks = 0; ks < 16; ++ks) {
    int kq = ks * 32 + lk * 8;
    f16x8 af[2], bf[2];
#pragma unroll
    for (int mi = 0; mi < 2; ++mi)
      af[mi] = *(const f16x8*)&Ab[(size_t)(h64 + wr * 32 + mi * 16 + lr) * CCH + kq];
#pragma unroll
    for (int ni = 0; ni < 2; ++ni)
      bf[ni] = *(const f16x8*)&Bb[(size_t)(wc * 32 + ni * 16 + lr) * CCH + kq];
#pragma unroll
    for (int mi = 0; mi < 2; ++mi)
#pragma unroll
      for (int ni = 0; ni < 2; ++ni)
        lacc[mi][ni] = __builtin_amdgcn_mfma_f32_16x16x32_f16(af[mi], bf[ni], lacc[mi][ni], 0, 0, 0);
  }
  __syncthreads();   // suq/suk ready
#pragma unroll
  for (int mi = 0; mi < 2; ++mi)
#pragma unroll
    for (int ni = 0; ni < 2; ++ni)
#pragma unroll
      for (int j = 0; j < 4; ++j) {
        int d = wr * 32 + mi * 16 + lk * 4 + j;
        int e = wc * 32 + ni * 16 + lr;
        Lsm[d][e] = (lacc[mi][ni][j] + suq[d] * sbk[e] + sbq[d] * suk[e]
                     + 16384.f * sbq[d] * sbk[e]) * 0.125f;
      }
  __syncthreads();
  // softmax per row d (t<64) -> Psm fp16 + pbv
  if (t < 64) {
    float m = -1e30f;
#pragma unroll
    for (int e = 0; e < 64; ++e) m = fmaxf(m, Lsm[t][e]);
    float p[64];
    float sum = 0.f;
#pragma unroll
    for (int e = 0; e < 64; ++e) { p[e] = expf(Lsm[t][e] - m); sum += p[e]; }
    float r = 1.f / sum, pb = 0.f;
#pragma unroll
    for (int e = 0; e < 64; ++e) {
      float pv = p[e] * r;
      Psm[t][e] = (f16)pv;
      pb += pv * sbv[e];
    }
    pbv[b * CCH + h64 + t] = pb;
  }
  __syncthreads();
  // PV MFMA: wave w owns c-chunk [w*128, w*128+128), full d; K = 64 (2 steps)
  f32x4 acc[4][8] = {};
  int c0w = wid * 128;
#pragma unroll
  for (int kk = 0; kk < 2; ++kk) {
    int e0 = kk * 32 + lk * 8;
    f16x8 pa[4], wb[8];
#pragma unroll
    for (int mi = 0; mi < 4; ++mi)
      pa[mi] = *(const f16x8*)&Psm[mi * 16 + lr][e0];
#pragma unroll
    for (int ni = 0; ni < 8; ++ni)
      wb[ni] = *(const f16x8*)&Wvt16[(size_t)(c0w + ni * 16 + lr) * CCH + h64 + e0];
#pragma unroll
    for (int mi = 0; mi < 4; ++mi)
#pragma unroll
      for (int ni = 0; ni < 8; ++ni)
        acc[mi][ni] = __builtin_amdgcn_mfma_f32_16x16x32_f16(pa[mi], wb[ni], acc[mi][ni], 0, 0, 0);
  }
  // C layout: col(lane&15) = c-within-tile, row((lane>>4)*4+j) = d-within-tile
  // -> lane holds 4 consecutive d for fixed c: 8B store into Rt16 row c.
#pragma unroll
  for (int mi = 0; mi < 4; ++mi)
#pragma unroll
    for (int ni = 0; ni < 8; ++ni) {
      int d0 = mi * 16 + lk * 4;
      int c = c0w + ni * 16 + lr;
      f16 hv[4] __attribute__((aligned(8)));
#pragma unroll
      for (int j = 0; j < 4; ++j) hv[j] = (f16)acc[mi][ni][j];
      *(uint2*)&Rt16[((size_t)b * CCH + c) * CCH + h64 + d0] = *(const uint2*)hv;
    }
}

// ---------------- K4d: cvec = out_w @ pbv + out_b (4 lanes/output) ----------------
__global__ __launch_bounds__(256) void k_cvec(const float* __restrict__ outw,
                                              const float* __restrict__ outb,
                                              const float* __restrict__ pbv,
                                              float* __restrict__ cvec) {
  int o = blockIdx.x * 64 + (threadIdx.x >> 2);   // grid.x = 8
  int l = threadIdx.x & 3;
  int b = blockIdx.y;
  __shared__ float sp[512];
  for (int i = threadIdx.x; i < 512; i += 256) sp[i] = pbv[b * CCH + i];
  __syncthreads();
  const float* wr_ = outw + (size_t)o * CCH + l * 128;
  const float* spp = sp + l * 128;
  float a = 0.f;
#pragma unroll
  for (int i = 0; i < 32; ++i) {
    float4 w = *(const float4*)&wr_[i * 4];
    a += w.x * spp[i * 4] + w.y * spp[i * 4 + 1] + w.z * spp[i * 4 + 2] + w.w * spp[i * 4 + 3];
  }
  a += __shfl_down(a, 2);
  a += __shfl_down(a, 1);
  if (l == 0) cvec[b * CCH + o] = a + outb[o];
}

// ---------------- K6: out = x + M16 @ H + cvec (fp16 MFMA, transposed fragment) ----
__global__ __launch_bounds__(256, 2) void k_out(const f16* __restrict__ M16,
                                                const f16* __restrict__ Ht,
                                                const float* __restrict__ x,
                                                const float* __restrict__ cvec,
                                                float* __restrict__ out) {
  int nt = blockIdx.x;   // 128 n-tiles
  int mt = blockIdx.y;   // 4 o-tiles
  int b = blockIdx.z;
  int m0 = mt * 128, n0 = nt * 128;
  int t = threadIdx.x, lane = t & 63, wid = t >> 6;
  int wr = wid >> 1, wc = wid & 1;
  __shared__ __align__(16) f16 sA[128 * 64];
  __shared__ __align__(16) f16 sB[128 * 64];
  const f16* A = M16 + (size_t)b * CCH * CCH;
  const f16* Bp = Ht + (size_t)b * NTOK * CCH;
  f32x4 acc[4][4] = {};
  int ldsrow = wid * 8 + (lane >> 3);
  int slot = lane & 7;
  int lr = lane & 15, lk = lane >> 4;
  for (int ks = 0; ks < 8; ++ks) {
    int kk0 = ks * 64;
    __syncthreads();
#pragma unroll
    for (int i = 0; i < 4; ++i) {
      int row = ldsrow + i * 32;
      int cA = ((slot ^ (row & 7)) * 8);
      g2l16(A + (size_t)(m0 + row) * CCH + kk0 + cA, &sA[i * 2048 + wid * 512]);
      g2l16(Bp + (size_t)(n0 + row) * CCH + kk0 + cA, &sB[i * 2048 + wid * 512]);
    }
    asm volatile("s_waitcnt vmcnt(0)" ::: "memory");
    __syncthreads();
#pragma unroll
    for (int kk = 0; kk < 2; ++kk) {
      f16x8 af[4], bf[4];
#pragma unroll
      for (int mi = 0; mi < 4; ++mi) {
        int row = wr * 64 + mi * 16 + lr;
        int ks8 = (kk * 4 + lk) ^ (row & 7);
        af[mi] = *(const f16x8*)&sA[row * 64 + ks8 * 8];
      }
#pragma unroll
      for (int ni = 0; ni < 4; ++ni) {
        int row = wc * 64 + ni * 16 + lr;
        int ks8 = (kk * 4 + lk) ^ (row & 7);
        bf[ni] = *(const f16x8*)&sB[row * 64 + ks8 * 8];
      }
#pragma unroll
      for (int mi = 0; mi < 4; ++mi)
#pragma unroll
        for (int ni = 0; ni < 4; ++ni)   // swapped: D[n][o] fragment
          acc[mi][ni] = __builtin_amdgcn_mfma_f32_16x16x32_f16(bf[ni], af[mi], acc[mi][ni], 0, 0, 0);
    }
  }

  const float* xb = x + ((size_t)b * CCH) * NTOK;
  float* ob = out + ((size_t)b * CCH) * NTOK;
#pragma unroll
  for (int mi = 0; mi < 4; ++mi) {
    int o = m0 + wr * 64 + mi * 16 + lr;
    float cv = cvec[b * CCH + o];
    size_t rowoff = (size_t)o * NTOK;
#pragma unroll
    for (int ni = 0; ni < 4; ++ni) {
      int n = n0 + wc * 64 + ni * 16 + lk * 4;
      float4 xv = *(const float4*)&xb[rowoff + n];
      float4 ov;
      ov.x = xv.x + acc[mi][ni][0] + cv;
      ov.y = xv.y + acc[mi][ni][1] + cv;
      ov.z = xv.z + acc[mi][ni][2] + cv;
      ov.w = xv.w + acc[mi][ni][3] + cv;
      *(float4*)&ob[rowoff + n] = ov;
    }
  }
}

extern "C" void kernel_launch(void* const* d_in, const int* in_sizes, int n_in,
                              void* d_out, int out_size, void* d_ws, size_t ws_size,
                              hipStream_t stream) {
  const float* x    = (const float*)d_in[0];
  const float* gw   = (const float*)d_in[1];
  const float* gb   = (const float*)d_in[2];
  const float* qkvw = (const float*)d_in[3];
  const float* qkvb = (const float*)d_in[4];
  const float* outw = (const float*)d_in[5];
  const float* outb = (const float*)d_in[6];
  int B = in_sizes[0] / (CCH * NTOK);   // 4

  char* ws = (char*)d_ws;
  size_t off = 0;
  f16* H      = (f16*)(ws + off);   off += (size_t)B * CCH * NTOK * 2;   // 64 MiB
  f16* Ht     = (f16*)(ws + off);   off += (size_t)B * NTOK * CCH * 2;   // 64 MiB
  float* G    = (float*)(ws + off); off += (size_t)B * CCH * CCH * 4;    // 4 MiB
  f16* G16    = (f16*)(ws + off);   off += (size_t)B * CCH * CCH * 2;    // 2 MiB
  f16* T1h    = (f16*)(ws + off);   off += (size_t)B * CCH * CCH * 2;    // 2 MiB
  f16* Rt16   = (f16*)(ws + off);   off += (size_t)B * CCH * CCH * 2;    // 2 MiB
  f16* M16    = (f16*)(ws + off);   off += (size_t)B * CCH * CCH * 2;    // 2 MiB
  f16* Wqkv16 = (f16*)(ws + off);   off += (size_t)3 * CCH * CCH * 2;    // 1.5 MiB
  f16* Ow16   = (f16*)(ws + off);   off += (size_t)CCH * CCH * 2;        // 0.5 MiB
  f16* Wvt16  = (f16*)(ws + off);   off += (size_t)CCH * CCH * 2;        // 0.5 MiB
  float* pbv  = (float*)(ws + off); off += (size_t)B * CCH * 4;
  float* cvec = (float*)(ws + off); off += (size_t)B * CCH * 4;
  // zero-init region: stats, svec (contiguous -> single memset)
  float* stats = (float*)(ws + off); off += (size_t)B * 8 * 2 * 4;
  float* svec  = (float*)(ws + off); off += (size_t)B * CCH * 4;
  size_t zbytes = (size_t)(B * 8 * 2 + B * CCH) * 4;

  hipMemsetAsync(G, 0, (size_t)B * CCH * CCH * 4, stream);
  hipMemsetAsync(stats, 0, zbytes, stream);

  k_cast2<<<dim3(3 * CCH * CCH / 1024, 2), 256, 0, stream>>>(qkvw, Wqkv16, outw, Ow16);
  k_wvt<<<dim3(8, 8), 256, 0, stream>>>(qkvw, Wvt16);
  k_stats<<<dim3(32, B * 8), 256, 0, stream>>>(x, stats);
  k_gnorm<<<dim3(64, 8, B), 256, 0, stream>>>(x, gw, gb, stats, H, Ht, svec);
  k_syrk<<<dim3(10, SPLITS, B), 256, 0, stream>>>(H, G);
  k_symm<<<dim3(40, B), 256, 0, stream>>>(G, G16);
  // T1h = fp16(Wq @ G + 16384*Wq)  (B-operand = G16 via symmetry)
  k_hgemm512<true, true><<<dim3(4, 4, B), 256, 0, stream>>>(Wqkv16, G16, T1h, qkvw);
  k_attn<<<dim3(NHEAD, B), 256, 0, stream>>>(T1h, Wqkv16, Wvt16, qkvw, qkvb, svec,
                                             Rt16, pbv);
  // M16 = out_w @ R  (B-operand = Rt16, already transposed)
  k_hgemm512<true, false><<<dim3(4, 4, B), 256, 0, stream>>>(Ow16, Rt16, M16, nullptr);
  k_cvec<<<dim3(8, B), 256, 0, stream>>>(outw, outb, pbv, cvec);
  k_out<<<dim3(128, 4, B), 256, 0, stream>>>(M16, Ht, x, cvec, (float*)d_out);
}